// Round 24
// baseline (329.250 us; speedup 1.0000x reference)
//
#include <hip/hip_runtime.h>
#include <math.h>

// Dims
constexpr int Bn = 4, Cc = 128, Hh = 128, Wn = 128, Dd = 48;
constexpr float SCALE = 0.25f;       // 16^-0.5

typedef short  bf16x8 __attribute__((ext_vector_type(8)));
typedef short  bf16x4 __attribute__((ext_vector_type(4)));
typedef float  f32x4  __attribute__((ext_vector_type(4)));
typedef unsigned short u16x8 __attribute__((ext_vector_type(8)));

static __device__ __forceinline__ unsigned short f2bf(float f) {
    return __builtin_bit_cast(unsigned short, (__bf16)f);
}
static __device__ __forceinline__ float bf2f(unsigned short u) {
    return __uint_as_float((unsigned int)u << 16);
}
static __device__ __forceinline__ unsigned int pack2bf(float a, float b) {
    return (unsigned int)f2bf(a) | ((unsigned int)f2bf(b) << 16);
}
static __device__ __forceinline__ float gelu_f(float v) {
    float u = v * (1.5957691216f + 0.0713548162f * v * v);
    return v * __builtin_amdgcn_rcpf(1.0f + __expf(-u));
}

// Packed-o address: fragment (Mt,ks), lane l, window (b,wh,ww).
static __device__ __forceinline__ size_t opk_addr(int b, int wh, int ww, int Mt, int ks, int lane) {
    return ((size_t)(b * 16384) + (wh * 8 + Mt * 2 + (ks >> 1)) * 128 + ww * 8) * 128
           + (ks & 1) * 512 + lane * 8;
}

// ---------------------------------------------------------------------------
// K1: cost volume -> bf16 pixel-major [b][h][w][64] (d 48..63 zero-padded).
// LDS-FREE: per thread 4w x 4d, 3 direct global float4 loads per channel;
// no barriers -> compiler software-pipelines, L1 serves the overlapping rows.
// Summation order (ascending c) identical to the staged version.
__global__ __launch_bounds__(192) void k_cost(const float* __restrict__ fl,
                                              const float* __restrict__ fr,
                                              unsigned short* __restrict__ costbf) {
    int tid = threadIdx.x;
    int w0 = blockIdx.x * 64;
    int h = blockIdx.y, b = blockIdx.z;
    int wg = tid & 15, dg = tid >> 4;      // wg 0..15, dg 0..11
    int W = wg * 4, D = dg * 4;

    const float* flp = fl + (((size_t)(b * 128)) << 14) + h * 128 + w0 + W;
    int fr_off = w0 + W - D - 4;           // multiple of 4
    const float* frp = fr + (((size_t)(b * 128)) << 14) + h * 128 + fr_off;
    bool ok0 = fr_off >= 0;
    bool ok1 = (fr_off + 4) >= 0;

    float acc[4][4];
#pragma unroll
    for (int i = 0; i < 4; ++i)
#pragma unroll
        for (int j = 0; j < 4; ++j) acc[i][j] = 0.f;

    const float4 z4 = {0.f, 0.f, 0.f, 0.f};
#pragma unroll 4
    for (int c = 0; c < 128; ++c) {
        size_t coff = (size_t)c << 14;
        float4 flv = *(const float4*)(flp + coff);
        float4 f0 = ok0 ? *(const float4*)(frp + coff) : z4;
        float4 f1 = ok1 ? *(const float4*)(frp + coff + 4) : z4;
        float fw[8] = {f0.x, f0.y, f0.z, f0.w, f1.x, f1.y, f1.z, f1.w};
        float fv[4] = {flv.x, flv.y, flv.z, flv.w};
#pragma unroll
        for (int dj = 0; dj < 4; ++dj)
#pragma unroll
            for (int wv = 0; wv < 4; ++wv)
                acc[dj][wv] += fv[wv] * fw[wv - dj + 4];
    }

    const float inv = 1.0f / 128.0f;
    unsigned short* cb = costbf + ((size_t)(b << 14) + h * 128 + w0 + W) * 64;
    const u16x8 z8 = {0, 0, 0, 0, 0, 0, 0, 0};
#pragma unroll
    for (int wv = 0; wv < 4; ++wv) {
        bf16x4 o4;
#pragma unroll
        for (int dj = 0; dj < 4; ++dj) o4[dj] = (short)f2bf(acc[dj][wv] * inv);
        *(bf16x4*)&cb[wv * 64 + D] = o4;
        if (D == 44) {
            *(u16x8*)&cb[wv * 64 + 48] = z8;
            *(u16x8*)&cb[wv * 64 + 56] = z8;
        }
    }
}

// ---------------------------------------------------------------------------
// Pack helpers fused into one kernel.
static __device__ void pack_conv(int blk, int lane,
                                 const float* __restrict__ w1, const float* __restrict__ b1,
                                 const float* __restrict__ bng, const float* __restrict__ bnb,
                                 unsigned short* __restrict__ pk, float* __restrict__ bias2) {
    const float rs = 0.9999950000374997f;
    int ct = blk % 6;
    int taplin = blk / 6;
    int tap = taplin % 9, chunk = taplin / 9;
    int co = ct * 16 + (lane & 15);
    int cibase = chunk * 32 + (lane >> 4) * 8;
    u16x8 out;
#pragma unroll
    for (int j = 0; j < 8; ++j) {
        int ci = cibase + j;
        float v = 0.f;
        if (co < 88 && ci < 176) v = w1[(size_t)co * 1584 + ci * 9 + tap] * rs * bng[co];
        out[j] = f2bf(v);
    }
    *(u16x8*)(pk + ((size_t)blk * 64 + lane) * 8) = out;
    if (blk == 0) {
        for (int i = lane; i < 96; i += 64)
            bias2[i] = (i < 88) ? (b1[i] * rs * bng[i] + bnb[i]) : 0.f;
    }
}

static __device__ void pack_gemmB(int blk, int lane,
                                  const float* __restrict__ W,
                                  unsigned short* __restrict__ out, int ncols) {
    int ntiles = ncols >> 4;
    int ks = blk & 3;
    int nt = (blk >> 2) % ntiles;
    int kc = blk / (4 * ntiles);
    int col = nt * 16 + (lane & 15);
    int k0 = kc * 128 + ks * 32 + (lane >> 4) * 8;
    u16x8 o;
#pragma unroll
    for (int j = 0; j < 8; ++j) o[j] = f2bf(W[(size_t)(k0 + j) * ncols + col]);
    *(u16x8*)(out + ((size_t)blk * 64 + lane) * 8) = o;
}

// rpb packed for the TRANSPOSED score layout.
static __device__ void pack_rpb(int blk, int lane,
                                const float* __restrict__ rpb, float* __restrict__ pb) {
    int nt = blk & 3, mt = (blk >> 2) & 3, hh = blk >> 4;
    int tq = nt * 16 + (lane & 15);
    int g = lane >> 4;
    float o[4];
#pragma unroll
    for (int rr = 0; rr < 4; ++rr) {
        int tk = mt * 16 + g * 4 + rr;
        int relidx = (((tq >> 3) - (tk >> 3)) + 7) * 15 + ((tq & 7) - (tk & 7)) + 7;
        o[rr] = rpb[relidx * 8 + hh];
    }
    float4 v = {o[0], o[1], o[2], o[3]};
    *(float4*)(pb + ((size_t)blk * 64 + lane) * 4) = v;
}

__global__ __launch_bounds__(64) void k_pack_all(
        const float* __restrict__ dp_w1, const float* __restrict__ dp_b1,
        const float* __restrict__ bn_g, const float* __restrict__ bn_b,
        unsigned short* __restrict__ pk, float* __restrict__ bias2,
        const float* __restrict__ wq, const float* __restrict__ wk,
        const float* __restrict__ wv, const float* __restrict__ wp,
        unsigned short* __restrict__ pkw,
        const float* __restrict__ rpb, float* __restrict__ pb,
        const float* __restrict__ mlp_w1, unsigned short* __restrict__ pm1,
        const float* __restrict__ mlp_w2, unsigned short* __restrict__ pm2,
        const float* __restrict__ un_w1, unsigned short* __restrict__ pu1,
        const float* __restrict__ un_w2, unsigned short* __restrict__ pu2,
        const float* __restrict__ dp_w2, unsigned short* __restrict__ w2a) {
    int blk = blockIdx.x;
    int lane = threadIdx.x;
    if (blk < 324) {
        pack_conv(blk, lane, dp_w1, dp_b1, bn_g, bn_b, pk, bias2);
    } else if (blk < 452) {
        int bb = blk - 324;
        int mat = bb >> 5;
        const float* W = (mat == 0) ? wq : (mat == 1) ? wk : (mat == 2) ? wv : wp;
        pack_gemmB(bb & 31, lane, W, pkw + (size_t)mat * 16384, 128);
    } else if (blk < 580) {
        pack_rpb(blk - 452, lane, rpb, pb);
    } else if (blk < 708) {
        pack_gemmB(blk - 580, lane, mlp_w1, pm1, 512);
    } else if (blk < 836) {
        pack_gemmB(blk - 708, lane, mlp_w2, pm2, 128);
    } else if (blk < 868) {
        pack_gemmB(blk - 836, lane, un_w1, pu1, 128);
    } else if (blk < 900) {
        pack_gemmB(blk - 868, lane, un_w2, pu2, 128);
    } else {
        // w2a: bf16 row-major [48][96]; w2a[d][k] = dp_w2[d][k] (k<88), else 0.
        for (int i = lane; i < 4608; i += 64) {
            int d = i / 96, k = i - d * 96;
            float v = (k < 88) ? dp_w2[d * 88 + k] : 0.f;
            w2a[i] = f2bf(v);
        }
    }
}

// ---------------------------------------------------------------------------
// K2: unary MLP via MFMA + LN1 producer. 1024 blocks x 64 tokens, 4 waves.
// Writes xu in bf16 (token-major) + nf = LN1(tok) (token-major bf16).
__global__ __launch_bounds__(256) void k_unary_mfma(const float* __restrict__ feat_l,
                                                    const unsigned short* __restrict__ pu1,
                                                    const float* __restrict__ b1,
                                                    const unsigned short* __restrict__ pu2,
                                                    const float* __restrict__ b2,
                                                    const float* __restrict__ g1,
                                                    const float* __restrict__ bt1,
                                                    unsigned short* __restrict__ xu,
                                                    unsigned short* __restrict__ nf) {
    __shared__ __align__(16) unsigned short s_a[64 * 136];
    __shared__ __align__(16) unsigned short s_h[64 * 136];
    int tid = threadIdx.x;
    int wid = tid >> 6, lane = tid & 63;
    int g = lane >> 4, t = lane & 15;
    int n0g = blockIdx.x * 64;
    int b = n0g >> 14;
    int nb = n0g & 16383;

    for (int idx = tid; idx < 4096; idx += 256) {
        int c2 = idx >> 6, nl = idx & 63;
        float v0 = feat_l[((size_t)(b * 128 + 2 * c2) << 14) + nb + nl];
        float v1 = feat_l[((size_t)(b * 128 + 2 * c2 + 1) << 14) + nb + nl];
        *(unsigned int*)&s_a[nl * 136 + 2 * c2] = pack2bf(v0, v1);
    }
    __syncthreads();

    // ---- LN1 -> nf (token-major bf16) ----
    {
        int tok = tid >> 2, q = tid & 3;
        float v[32];
#pragma unroll
        for (int i8 = 0; i8 < 4; ++i8) {
            u16x8 r8 = *(const u16x8*)&s_a[tok * 136 + q * 32 + i8 * 8];
#pragma unroll
            for (int j = 0; j < 8; ++j) v[i8 * 8 + j] = bf2f(r8[j]);
        }
        float s = 0.f, s2 = 0.f;
#pragma unroll
        for (int i = 0; i < 32; ++i) { s += v[i]; s2 += v[i] * v[i]; }
        s += __shfl_xor(s, 1); s += __shfl_xor(s, 2);
        s2 += __shfl_xor(s2, 1); s2 += __shfl_xor(s2, 2);
        float mean = s * (1.f / 128.f);
        float var = s2 * (1.f / 128.f) - mean * mean;
        float rstd = rsqrtf(var + 1e-5f);
        size_t base = (size_t)(n0g + tok) * 128 + q * 32;
#pragma unroll
        for (int i8 = 0; i8 < 4; ++i8) {
            u16x8 o8;
#pragma unroll
            for (int j = 0; j < 8; ++j) {
                int c = q * 32 + i8 * 8 + j;
                o8[j] = f2bf((v[i8 * 8 + j] - mean) * rstd * g1[c] + bt1[c]);
            }
            *(u16x8*)&nf[base + i8 * 8] = o8;
        }
    }

    bf16x8 af[4][4];
#pragma unroll
    for (int Mt = 0; Mt < 4; ++Mt)
#pragma unroll
        for (int ks = 0; ks < 4; ++ks)
            af[Mt][ks] = *(const bf16x8*)&s_a[(Mt * 16 + t) * 136 + ks * 32 + g * 8];

    f32x4 acc1[4][2];
#pragma unroll
    for (int nt2 = 0; nt2 < 2; ++nt2) {
        float bv = b1[(wid * 2 + nt2) * 16 + t];
#pragma unroll
        for (int Mt = 0; Mt < 4; ++Mt) acc1[Mt][nt2] = (f32x4){bv, bv, bv, bv};
    }
#pragma unroll
    for (int ks = 0; ks < 4; ++ks) {
        bf16x8 bf0 = *(const bf16x8*)(pu1 + (size_t)(((wid * 2 + 0) * 4 + ks) * 64 + lane) * 8);
        bf16x8 bf1 = *(const bf16x8*)(pu1 + (size_t)(((wid * 2 + 1) * 4 + ks) * 64 + lane) * 8);
#pragma unroll
        for (int Mt = 0; Mt < 4; ++Mt) {
            acc1[Mt][0] = __builtin_amdgcn_mfma_f32_16x16x32_bf16(af[Mt][ks], bf0, acc1[Mt][0], 0, 0, 0);
            acc1[Mt][1] = __builtin_amdgcn_mfma_f32_16x16x32_bf16(af[Mt][ks], bf1, acc1[Mt][1], 0, 0, 0);
        }
    }
#pragma unroll
    for (int Mt = 0; Mt < 4; ++Mt)
#pragma unroll
        for (int nt2 = 0; nt2 < 2; ++nt2)
#pragma unroll
            for (int rr = 0; rr < 4; ++rr)
                s_h[(Mt * 16 + g * 4 + rr) * 136 + (wid * 2 + nt2) * 16 + t] = f2bf(gelu_f(acc1[Mt][nt2][rr]));
    __syncthreads();

    bf16x8 a2[4][4];
#pragma unroll
    for (int Mt = 0; Mt < 4; ++Mt)
#pragma unroll
        for (int ks = 0; ks < 4; ++ks)
            a2[Mt][ks] = *(const bf16x8*)&s_h[(Mt * 16 + t) * 136 + ks * 32 + g * 8];

    f32x4 acc2[4][2];
#pragma unroll
    for (int nt2 = 0; nt2 < 2; ++nt2) {
        float bv = b2[(wid * 2 + nt2) * 16 + t];
#pragma unroll
        for (int Mt = 0; Mt < 4; ++Mt) acc2[Mt][nt2] = (f32x4){bv, bv, bv, bv};
    }
#pragma unroll
    for (int ks = 0; ks < 4; ++ks) {
        bf16x8 bf0 = *(const bf16x8*)(pu2 + (size_t)(((wid * 2 + 0) * 4 + ks) * 64 + lane) * 8);
        bf16x8 bf1 = *(const bf16x8*)(pu2 + (size_t)(((wid * 2 + 1) * 4 + ks) * 64 + lane) * 8);
#pragma unroll
        for (int Mt = 0; Mt < 4; ++Mt) {
            acc2[Mt][0] = __builtin_amdgcn_mfma_f32_16x16x32_bf16(a2[Mt][ks], bf0, acc2[Mt][0], 0, 0, 0);
            acc2[Mt][1] = __builtin_amdgcn_mfma_f32_16x16x32_bf16(a2[Mt][ks], bf1, acc2[Mt][1], 0, 0, 0);
        }
    }
#pragma unroll
    for (int Mt = 0; Mt < 4; ++Mt)
#pragma unroll
        for (int nt2 = 0; nt2 < 2; ++nt2)
#pragma unroll
            for (int rr = 0; rr < 4; ++rr) {
                int tok = Mt * 16 + g * 4 + rr;
                xu[(size_t)(n0g + tok) * 128 + (wid * 2 + nt2) * 16 + t] = f2bf(acc2[Mt][nt2][rr]);
            }
}

// ---------------------------------------------------------------------------
// K3: attention core (S^T = K Q^T form). 1024 blocks, 256 threads (4 waves).
__global__ __launch_bounds__(256, 3) void k_attn_core(const unsigned short* nf,
                                                      const unsigned short* __restrict__ pkw,
                                                      const float* __restrict__ pb,
                                                      const float* __restrict__ bq,
                                                      const float* __restrict__ bk,
                                                      const float* __restrict__ bv,
                                                      unsigned short* opk) {
    __shared__ __align__(16) unsigned short s_all[4 * 5760];
    int tid = threadIdx.x;
    int wid = tid >> 6, lane = tid & 63;
    int g = lane >> 4, t = lane & 15;
    int bw = blockIdx.x;
    int b = bw >> 8, wh = (bw >> 4) & 15, ww = bw & 15;

    bf16x8 af[4][4];   // [Mt][ks]
#pragma unroll
    for (int Mt = 0; Mt < 4; ++Mt) {
        int tok = Mt * 16 + t;
        size_t gtok = (size_t)(b * 16384) + (wh * 8 + (tok >> 3)) * 128 + ww * 8 + (tok & 7);
#pragma unroll
        for (int ks = 0; ks < 4; ++ks)
            af[Mt][ks] = *(const bf16x8*)&nf[gtok * 128 + ks * 32 + g * 8];
    }
    __syncthreads();

    unsigned short* sQ = s_all + wid * 5760;
    unsigned short* sK = sQ + 1536;
    unsigned short* sV = sQ + 4608;
    unsigned short* sP = sQ;
    unsigned short* sO = sQ;

    const bf16x8 z8v = {0, 0, 0, 0, 0, 0, 0, 0};

#pragma unroll
    for (int hi = 0; hi < 2; ++hi) {
        int h = wid + hi * 4;

        float bqv = bq[h * 16 + t], bkv = bk[h * 16 + t], bvv = bv[h * 16 + t];
        f32x4 qa[4], ka[4], va[4];
#pragma unroll
        for (int Mt = 0; Mt < 4; ++Mt) {
            qa[Mt] = (f32x4){bqv, bqv, bqv, bqv};
            ka[Mt] = (f32x4){bkv, bkv, bkv, bkv};
            va[Mt] = (f32x4){bvv, bvv, bvv, bvv};
        }
#pragma unroll
        for (int ks = 0; ks < 4; ++ks) {
            const unsigned short* wbase = pkw + ((size_t)((h * 4 + ks) * 64 + lane) * 8);
            bf16x8 bfq = *(const bf16x8*)(wbase);
            bf16x8 bfk = *(const bf16x8*)(wbase + 16384);
            bf16x8 bfv = *(const bf16x8*)(wbase + 32768);
#pragma unroll
            for (int Mt = 0; Mt < 4; ++Mt) {
                qa[Mt] = __builtin_amdgcn_mfma_f32_16x16x32_bf16(af[Mt][ks], bfq, qa[Mt], 0, 0, 0);
                ka[Mt] = __builtin_amdgcn_mfma_f32_16x16x32_bf16(af[Mt][ks], bfk, ka[Mt], 0, 0, 0);
                va[Mt] = __builtin_amdgcn_mfma_f32_16x16x32_bf16(af[Mt][ks], bfv, va[Mt], 0, 0, 0);
            }
        }
#pragma unroll
        for (int Mt = 0; Mt < 4; ++Mt) {
            bf16x4 vv;
#pragma unroll
            for (int rr = 0; rr < 4; ++rr) {
                int tok = Mt * 16 + g * 4 + rr;
                sQ[tok * 24 + t] = f2bf(qa[Mt][rr] * SCALE);
                sK[tok * 24 + t] = f2bf(ka[Mt][rr]);
                vv[rr] = (short)f2bf(va[Mt][rr]);
            }
            *(bf16x4*)&sV[t * 72 + Mt * 16 + g * 4] = vv;
        }

        // ---- S^T = K Q^T + bias(C-init); pad lanes (g>=2) feed zeros ----
        f32x4 s[4][4];   // [Mtk][Ntq]
#pragma unroll
        for (int Mtk = 0; Mtk < 4; ++Mtk)
#pragma unroll
            for (int Ntq = 0; Ntq < 4; ++Ntq)
                s[Mtk][Ntq] = *(const f32x4*)(pb + ((size_t)((h * 16 + Mtk * 4 + Ntq) * 64 + lane) * 4));
        bf16x8 bQ[4];
#pragma unroll
        for (int Ntq = 0; Ntq < 4; ++Ntq)
            bQ[Ntq] = (g < 2) ? *(const bf16x8*)&sQ[(Ntq * 16 + t) * 24 + g * 8] : z8v;
#pragma unroll
        for (int Mtk = 0; Mtk < 4; ++Mtk) {
            bf16x8 aK = (g < 2) ? *(const bf16x8*)&sK[(Mtk * 16 + t) * 24 + g * 8] : z8v;
#pragma unroll
            for (int Ntq = 0; Ntq < 4; ++Ntq)
                s[Mtk][Ntq] = __builtin_amdgcn_mfma_f32_16x16x32_bf16(aK, bQ[Ntq], s[Mtk][Ntq], 0, 0, 0);
        }

        // ---- softmax: per-lane 16-reduce + 2 shuffles per q-tile ----
#pragma unroll
        for (int Ntq = 0; Ntq < 4; ++Ntq) {
            float m = s[0][Ntq][0];
#pragma unroll
            for (int Mtk = 0; Mtk < 4; ++Mtk)
#pragma unroll
                for (int rr = 0; rr < 4; ++rr) m = fmaxf(m, s[Mtk][Ntq][rr]);
            m = fmaxf(m, __shfl_xor(m, 16));
            m = fmaxf(m, __shfl_xor(m, 32));
            float sum = 0.f;
#pragma unroll
            for (int Mtk = 0; Mtk < 4; ++Mtk)
#pragma unroll
                for (int rr = 0; rr < 4; ++rr) {
                    float e = __expf(s[Mtk][Ntq][rr] - m);
                    s[Mtk][Ntq][rr] = e;
                    sum += e;
                }
            sum += __shfl_xor(sum, 16);
            sum += __shfl_xor(sum, 32);
            float inv = __builtin_amdgcn_rcpf(sum);
#pragma unroll
            for (int Mtk = 0; Mtk < 4; ++Mtk) {
                bf16x4 pv;
#pragma unroll
                for (int rr = 0; rr < 4; ++rr) pv[rr] = (short)f2bf(s[Mtk][Ntq][rr] * inv);
                *(bf16x4*)&sP[(Ntq * 16 + t) * 72 + Mtk * 16 + g * 4] = pv;
            }
        }

        // ---- O = P @ V ----
        f32x4 oa[4];
#pragma unroll
        for (int Mt = 0; Mt < 4; ++Mt) oa[Mt] = (f32x4){0.f, 0.f, 0.f, 0.f};
#pragma unroll
        for (int ksv = 0; ksv < 2; ++ksv) {
            bf16x8 bv2 = *(const bf16x8*)&sV[t * 72 + ksv * 32 + g * 8];
#pragma unroll
            for (int Mt = 0; Mt < 4; ++Mt) {
                bf16x8 ap = *(const bf16x8*)&sP[(Mt * 16 + t) * 72 + ksv * 32 + g * 8];
                oa[Mt] = __builtin_amdgcn_mfma_f32_16x16x32_bf16(ap, bv2, oa[Mt], 0, 0, 0);
            }
        }
#pragma unroll
        for (int Mt = 0; Mt < 4; ++Mt)
#pragma unroll
            for (int rr = 0; rr < 4; ++rr)
                sO[(Mt * 16 + g * 4 + rr) * 16 + t] = f2bf(oa[Mt][rr]);
        int ksf = h >> 1;
        if ((g >> 1) == (h & 1)) {
#pragma unroll
            for (int Mt = 0; Mt < 4; ++Mt) {
                bf16x8 v8 = *(const bf16x8*)&sO[(Mt * 16 + t) * 16 + (g & 1) * 8];
                *(bf16x8*)&opk[opk_addr(b, wh, ww, Mt, ksf, lane)] = v8;
            }
        }
    }
}

// ---------------------------------------------------------------------------
// K4: HALF-WINDOW block: xbf = bf16( (xu + o@wp + bp) + mlp(LN2(...)) ).
// grid 2048: blockIdx = window*2 + half. LDS 18.4 KB -> 8 blocks/CU.
__global__ __launch_bounds__(256) void k_mlp_mfma(const unsigned short* __restrict__ xu,
                                                  const unsigned short* opk,
                                                  const unsigned short* __restrict__ pkw,
                                                  const float* __restrict__ bp,
                                                  const float* __restrict__ g2,
                                                  const float* __restrict__ bt2,
                                                  const unsigned short* __restrict__ pm1,
                                                  const float* __restrict__ b1,
                                                  const unsigned short* __restrict__ pm2,
                                                  unsigned short* xbf) {
    __shared__ __align__(16) char smem[18432];
    float* sf = (float*)smem;                       // [32][132] f32 (16896 B)
    unsigned short* s_h = (unsigned short*)smem;    // [32][264] bf16 overlays sf
    float* s_st = (float*)(smem + 16896);           // [32][2] mean,rstd
    float* s_gb = (float*)(smem + 17152);           // g2[128] | bt2[128]
    int tid = threadIdx.x;
    int wid = tid >> 6, lane = tid & 63;
    int g = lane >> 4, t = lane & 15;
    int bw = blockIdx.x >> 1, half = blockIdx.x & 1;
    int b = bw >> 8, wh = (bw >> 4) & 15, ww = bw & 15;

    auto gtok_of = [&](int tok) -> size_t {   // tok: local 0..31
        int tg = half * 32 + tok;
        return (size_t)(b * 16384) + (wh * 8 + (tg >> 3)) * 128 + ww * 8 + (tg & 7);
    };

    if (tid < 128) s_gb[tid] = g2[tid];
    else if (tid < 256) s_gb[tid] = bt2[tid - 128];

    f32x4 out[2][2];
    {
        float bp0 = bp[wid * 32 + t], bp1 = bp[wid * 32 + 16 + t];
#pragma unroll
        for (int Mt = 0; Mt < 2; ++Mt) {
            out[Mt][0] = (f32x4){bp0, bp0, bp0, bp0};
            out[Mt][1] = (f32x4){bp1, bp1, bp1, bp1};
        }
#pragma unroll
        for (int ks = 0; ks < 4; ++ks) {
            bf16x8 b0 = *(const bf16x8*)(pkw + 49152 + (size_t)(((wid * 2 + 0) * 4 + ks) * 64 + lane) * 8);
            bf16x8 b1v = *(const bf16x8*)(pkw + 49152 + (size_t)(((wid * 2 + 1) * 4 + ks) * 64 + lane) * 8);
#pragma unroll
            for (int Mt = 0; Mt < 2; ++Mt) {
                bf16x8 a = *(const bf16x8*)&opk[opk_addr(b, wh, ww, half * 2 + Mt, ks, lane)];
                out[Mt][0] = __builtin_amdgcn_mfma_f32_16x16x32_bf16(a, b0, out[Mt][0], 0, 0, 0);
                out[Mt][1] = __builtin_amdgcn_mfma_f32_16x16x32_bf16(a, b1v, out[Mt][1], 0, 0, 0);
            }
        }
#pragma unroll
        for (int Mt = 0; Mt < 2; ++Mt)
#pragma unroll
            for (int nt2 = 0; nt2 < 2; ++nt2)
#pragma unroll
                for (int rr = 0; rr < 4; ++rr) {
                    int tok = Mt * 16 + g * 4 + rr;
                    int col = (wid * 2 + nt2) * 16 + t;
                    float v = out[Mt][nt2][rr] + bf2f(xu[gtok_of(tok) * 128 + col]);
                    out[Mt][nt2][rr] = v;
                    sf[tok * 132 + col] = v;
                }
    }
    __syncthreads();
    if (tid < 128) {
        int tok = tid >> 2, q = tid & 3;
        float s = 0.f, s2 = 0.f;
        for (int c = q * 32; c < q * 32 + 32; ++c) {
            float v = sf[tok * 132 + c];
            s += v; s2 += v * v;
        }
        s += __shfl_xor(s, 1); s += __shfl_xor(s, 2);
        s2 += __shfl_xor(s2, 1); s2 += __shfl_xor(s2, 2);
        if (q == 0) {
            float mean = s * (1.f / 128.f);
            float var = s2 * (1.f / 128.f) - mean * mean;
            s_st[tok * 2] = mean;
            s_st[tok * 2 + 1] = rsqrtf(var + 1e-5f);
        }
    }
    __syncthreads();
    bf16x8 af2[2][4];
#pragma unroll
    for (int Mt = 0; Mt < 2; ++Mt) {
        int tok = Mt * 16 + t;
        float mean = s_st[tok * 2], rstd = s_st[tok * 2 + 1];
#pragma unroll
        for (int ks = 0; ks < 4; ++ks) {
            int c0 = ks * 32 + g * 8;
            float4 v0 = *(const float4*)&sf[tok * 132 + c0];
            float4 v1 = *(const float4*)&sf[tok * 132 + c0 + 4];
            float vv[8] = {v0.x, v0.y, v0.z, v0.w, v1.x, v1.y, v1.z, v1.w};
            u16x8 o8;
#pragma unroll
            for (int j = 0; j < 8; ++j)
                o8[j] = f2bf((vv[j] - mean) * rstd * s_gb[c0 + j] + s_gb[128 + c0 + j]);
            af2[Mt][ks] = __builtin_bit_cast(bf16x8, o8);
        }
    }
    __syncthreads();

#pragma unroll 1
    for (int hc = 0; hc < 2; ++hc) {
#pragma unroll
        for (int jh = 0; jh < 2; ++jh) {
            f32x4 acc1[2][2];
#pragma unroll
            for (int j2 = 0; j2 < 2; ++j2) {
                float bv = b1[hc * 256 + (wid * 4 + jh * 2 + j2) * 16 + t];
#pragma unroll
                for (int Mt = 0; Mt < 2; ++Mt) acc1[Mt][j2] = (f32x4){bv, bv, bv, bv};
            }
#pragma unroll
            for (int ks = 0; ks < 4; ++ks) {
                int nt0 = hc * 16 + wid * 4 + jh * 2;
                bf16x8 bf0 = *(const bf16x8*)(pm1 + (size_t)((((nt0 + 0) * 4 + ks) * 64 + lane) * 8));
                bf16x8 bf1 = *(const bf16x8*)(pm1 + (size_t)((((nt0 + 1) * 4 + ks) * 64 + lane) * 8));
#pragma unroll
                for (int Mt = 0; Mt < 2; ++Mt) {
                    acc1[Mt][0] = __builtin_amdgcn_mfma_f32_16x16x32_bf16(af2[Mt][ks], bf0, acc1[Mt][0], 0, 0, 0);
                    acc1[Mt][1] = __builtin_amdgcn_mfma_f32_16x16x32_bf16(af2[Mt][ks], bf1, acc1[Mt][1], 0, 0, 0);
                }
            }
#pragma unroll
            for (int Mt = 0; Mt < 2; ++Mt)
#pragma unroll
                for (int j2 = 0; j2 < 2; ++j2)
#pragma unroll
                    for (int rr = 0; rr < 4; ++rr)
                        s_h[(Mt * 16 + g * 4 + rr) * 264 + (wid * 4 + jh * 2 + j2) * 16 + t] =
                            f2bf(gelu_f(acc1[Mt][j2][rr]));
        }
        __syncthreads();
#pragma unroll
        for (int kt = 0; kt < 8; ++kt) {
            int kc = hc * 2 + (kt >> 2), ks = kt & 3;
            bf16x8 bf0 = *(const bf16x8*)(pm2 + (size_t)(((kc * 32 + (wid * 2 + 0) * 4 + ks) * 64 + lane) * 8));
            bf16x8 bf1 = *(const bf16x8*)(pm2 + (size_t)(((kc * 32 + (wid * 2 + 1) * 4 + ks) * 64 + lane) * 8));
#pragma unroll
            for (int Mt = 0; Mt < 2; ++Mt) {
                bf16x8 a2 = *(const bf16x8*)&s_h[(Mt * 16 + t) * 264 + kt * 32 + g * 8];
                out[Mt][0] = __builtin_amdgcn_mfma_f32_16x16x32_bf16(a2, bf0, out[Mt][0], 0, 0, 0);
                out[Mt][1] = __builtin_amdgcn_mfma_f32_16x16x32_bf16(a2, bf1, out[Mt][1], 0, 0, 0);
            }
        }
        __syncthreads();
    }

    // final: xbf = bf16(x_pre_mlp + mlp_out)
#pragma unroll
    for (int Mt = 0; Mt < 2; ++Mt)
#pragma unroll
        for (int nt2 = 0; nt2 < 2; ++nt2)
#pragma unroll
            for (int rr = 0; rr < 4; ++rr) {
                int tok = Mt * 16 + g * 4 + rr;
                xbf[gtok_of(tok) * 128 + (wid * 2 + nt2) * 16 + t] = f2bf(out[Mt][nt2][rr]);
            }
}

// ---------------------------------------------------------------------------
// K5b: conv3x3 as bf16 implicit-GEMM MFMA. grid (8,16,4) = 512 blocks.
// Writes h1 PIXEL-MAJOR [pix][96]; co 88..95 ZEROED (read by MFMA head pad).
__global__ __launch_bounds__(256) void k_conv_mfma(const unsigned short* __restrict__ xbf,
                                                   const unsigned short* __restrict__ costbf,
                                                   const unsigned short* __restrict__ pk,
                                                   const float* __restrict__ bias2,
                                                   unsigned short* __restrict__ h1) {
    __shared__ __align__(16) unsigned short s_p[180 * 40];
    int tid = threadIdx.x;
    int wid = tid >> 6, lane = tid & 63;
    int g = lane >> 4, t = lane & 15;
    int tx0 = blockIdx.x * 16, ty0 = blockIdx.y * 8, b = blockIdx.z;

    f32x4 acc[2][6];
#pragma unroll
    for (int p = 0; p < 2; ++p)
#pragma unroll
        for (int ct = 0; ct < 6; ++ct) acc[p][ct] = (f32x4){0.f, 0.f, 0.f, 0.f};

#pragma unroll 1
    for (int chunk = 0; chunk < 6; ++chunk) {
        for (int u = tid; u < 180; u += 256) {
            int yy = u / 18, xx = u - yy * 18;
            int gy = ty0 + yy - 1, gx = tx0 + xx - 1;
            u16x8 v0 = (u16x8)(unsigned short)0, v1 = v0, v2 = v0, v3 = v0;
            if (gy >= 0 && gy < 128 && gx >= 0 && gx < 128) {
                size_t pix = (size_t)(b << 14) + gy * 128 + gx;
                const u16x8* src = (chunk < 4)
                    ? (const u16x8*)&xbf[pix * 128 + chunk * 32]
                    : (const u16x8*)&costbf[pix * 64 + (chunk - 4) * 32];
                v0 = src[0]; v1 = src[1]; v2 = src[2]; v3 = src[3];
            }
            *(u16x8*)&s_p[u * 40 + 0] = v0;
            *(u16x8*)&s_p[u * 40 + 8] = v1;
            *(u16x8*)&s_p[u * 40 + 16] = v2;
            *(u16x8*)&s_p[u * 40 + 24] = v3;
        }
        __syncthreads();

#pragma unroll 1
        for (int tap = 0; tap < 9; ++tap) {
            int dy = tap / 3, dx = tap - dy * 3;
            const unsigned short* pkt = pk + ((size_t)(chunk * 9 + tap)) * 6 * 512;
            bf16x8 afr[6];
#pragma unroll
            for (int ct = 0; ct < 6; ++ct)
                afr[ct] = *(const bf16x8*)(pkt + ct * 512 + lane * 8);
            bf16x8 bfr[2];
#pragma unroll
            for (int p = 0; p < 2; ++p) {
                int pos = (wid * 2 + p + dy) * 18 + t + dx;
                bfr[p] = *(const bf16x8*)&s_p[pos * 40 + g * 8];
            }
#pragma unroll
            for (int p = 0; p < 2; ++p)
#pragma unroll
                for (int ct = 0; ct < 6; ++ct)
                    acc[p][ct] = __builtin_amdgcn_mfma_f32_16x16x32_bf16(afr[ct], bfr[p], acc[p][ct], 0, 0, 0);
        }
        __syncthreads();
    }

#pragma unroll
    for (int p = 0; p < 2; ++p) {
        int y = ty0 + wid * 2 + p;
        size_t pix = (size_t)(b << 14) + y * 128 + tx0 + t;
#pragma unroll
        for (int ct = 0; ct < 6; ++ct) {
#pragma unroll
            for (int rr = 0; rr < 4; ++rr) {
                int co = ct * 16 + g * 4 + rr;
                if (co < 88) {
                    float v = acc[p][ct][rr] + bias2[co];
                    h1[pix * 96 + co] = f2bf(fmaxf(v, 0.f));
                } else {
                    h1[pix * 96 + co] = 0;
                }
            }
        }
    }
}

// ---------------------------------------------------------------------------
// K6: head as MFMA GEMM: pv[d=48][px] = w2a[48][96] @ h1^T[96][px] + b2.
// 256 blocks x 256 threads; each wave computes 64 px. C-layout: lane holds
// d = Mt*16+g*4+rr, px = nt*16+t -> softmax over d = per-lane 12-reduce +
// shfl_xor(16,32) across g groups. Lane g==0 writes pred.
__global__ __launch_bounds__(256) void k_head(const unsigned short* __restrict__ h1p,
                                              const unsigned short* __restrict__ w2a,
                                              const float* __restrict__ b2,
                                              float* __restrict__ out) {
    int tid = threadIdx.x;
    int wid = tid >> 6, lane = tid & 63;
    int g = lane >> 4, t = lane & 15;
    int pxb = blockIdx.x * 256 + wid * 64;

    bf16x8 afr[3][3];   // w2a [48][96] row-major: row = Mt*16+t, k = ks*32+g*8
#pragma unroll
    for (int Mt = 0; Mt < 3; ++Mt)
#pragma unroll
        for (int ks = 0; ks < 3; ++ks)
            afr[Mt][ks] = *(const bf16x8*)&w2a[(Mt * 16 + t) * 96 + ks * 32 + g * 8];

    f32x4 acc[3][4];
#pragma unroll
    for (int Mt = 0; Mt < 3; ++Mt) {
        f32x4 bv = *(const f32x4*)&b2[Mt * 16 + g * 4];
#pragma unroll
        for (int nt = 0; nt < 4; ++nt) acc[Mt][nt] = bv;
    }
#pragma unroll
    for (int ks = 0; ks < 3; ++ks) {
#pragma unroll
        for (int nt = 0; nt < 4; ++nt) {
            bf16x8 bfr = *(const bf16x8*)&h1p[(size_t)(pxb + nt * 16 + t) * 96 + ks * 32 + g * 8];
#pragma unroll
            for (int Mt = 0; Mt < 3; ++Mt)
                acc[Mt][nt] = __builtin_amdgcn_mfma_f32_16x16x32_bf16(afr[Mt][ks], bfr, acc[Mt][nt], 0, 0, 0);
        }
    }

#pragma unroll
    for (int nt = 0; nt < 4; ++nt) {
        float m = acc[0][nt][0];
#pragma unroll
        for (int Mt = 0; Mt < 3; ++Mt)
#pragma unroll
            for (int rr = 0; rr < 4; ++rr) m = fmaxf(m, acc[Mt][nt][rr]);
        m = fmaxf(m, __shfl_xor(m, 16));
        m = fmaxf(m, __shfl_xor(m, 32));
        float sum = 0.f, wsum = 0.f;
#pragma unroll
        for (int Mt = 0; Mt < 3; ++Mt)
#pragma unroll
            for (int rr = 0; rr < 4; ++rr) {
                float e = __expf(acc[Mt][nt][rr] - m);
                sum += e;
                wsum += e * (float)(Mt * 16 + g * 4 + rr);
            }
        sum += __shfl_xor(sum, 16);
        sum += __shfl_xor(sum, 32);
        wsum += __shfl_xor(wsum, 16);
        wsum += __shfl_xor(wsum, 32);
        if (g == 0)
            out[pxb + nt * 16 + t] = 4.0f * wsum * __builtin_amdgcn_rcpf(sum);
    }
}

// ---------------------------------------------------------------------------
extern "C" void kernel_launch(void* const* d_in, const int* in_sizes, int n_in,
                              void* d_out, int out_size, void* d_ws, size_t ws_size,
                              hipStream_t stream) {
    const float* feat_l = (const float*)d_in[0];
    const float* feat_r = (const float*)d_in[1];
    const float* wq = (const float*)d_in[2];
    const float* bq = (const float*)d_in[3];
    const float* wk = (const float*)d_in[4];
    const float* bk = (const float*)d_in[5];
    const float* wv = (const float*)d_in[6];
    const float* bv = (const float*)d_in[7];
    const float* wp = (const float*)d_in[8];
    const float* bp = (const float*)d_in[9];
    const float* rpb = (const float*)d_in[10];
    const float* ln1_g = (const float*)d_in[11];
    const float* ln1_b = (const float*)d_in[12];
    const float* ln2_g = (const float*)d_in[13];
    const float* ln2_b = (const float*)d_in[14];
    const float* mlp_w1 = (const float*)d_in[15];
    const float* mlp_b1 = (const float*)d_in[16];
    const float* mlp_w2 = (const float*)d_in[17];
    // d_in[18] = mlp_b2 is multiplied by 0.0 in the reference -> unused
    const float* un_w1 = (const float*)d_in[19];
    const float* un_b1 = (const float*)d_in[20];
    const float* un_w2 = (const float*)d_in[21];
    const float* un_b2 = (const float*)d_in[22];
    const float* dp_w1 = (const float*)d_in[23];
    const float* dp_b1 = (const float*)d_in[24];
    const float* bn_g = (const float*)d_in[25];
    const float* bn_b = (const float*)d_in[26];
    const float* dp_w2 = (const float*)d_in[27];
    const float* dp_b2 = (const float*)d_in[28];

    float* ws = (float*)d_ws;
    unsigned short* costbf = (unsigned short*)ws;   // 4*16384*64 u16 = 8.4 MB
    // xu (unary out, bf16, 16.8 MB) in the old x region; h1bf (pixel-major
    // [pix][96], 12.6 MB) overwrites it after k_mlp has consumed xu.
    unsigned short* xu = (unsigned short*)(ws + 3145728);
    unsigned short* h1bf = (unsigned short*)(ws + 3145728);
    // nf -> opk -> xbf all share this 16.8 MB region (per-window in-place).
    unsigned short* nfo = (unsigned short*)(ws + 11534336);
    unsigned short* pk = (unsigned short*)(ws + 17301504);       // 165,888 u16
    float* bias2 = ws + 17384448;                   // 96 f
    unsigned short* pkw = (unsigned short*)(ws + 17384544);      // 65,536 u16
    float* pb = ws + 17417312;                      // 32,768 f
    unsigned short* pm1 = (unsigned short*)(ws + 17450080);      // 65,536 u16
    unsigned short* pm2 = (unsigned short*)(ws + 17482848);      // 65,536 u16
    unsigned short* pu1 = (unsigned short*)(ws + 17515616);      // 16,384 u16
    unsigned short* pu2 = (unsigned short*)(ws + 17523808);      // 16,384 u16
    unsigned short* w2a = (unsigned short*)(ws + 17532000);      // 4,608 u16 (bf16 head A)
    float* out = (float*)d_out;

    k_pack_all<<<901, 64, 0, stream>>>(dp_w1, dp_b1, bn_g, bn_b, pk, bias2,
                                       wq, wk, wv, wp, pkw, rpb, pb,
                                       mlp_w1, pm1, mlp_w2, pm2,
                                       un_w1, pu1, un_w2, pu2,
                                       dp_w2, w2a);
    k_cost<<<dim3(2, 128, 4), 192, 0, stream>>>(feat_l, feat_r, costbf);
    k_unary_mfma<<<1024, 256, 0, stream>>>(feat_l, pu1, un_b1, pu2, un_b2,
                                           ln1_g, ln1_b, xu, nfo);
    k_attn_core<<<1024, 256, 0, stream>>>(nfo, pkw, pb, bq, bk, bv, nfo);
    // k_mlp (half-window blocks) reads xu(bf16) + opk(nfo), writes xbf IN PLACE
    k_mlp_mfma<<<2048, 256, 0, stream>>>(xu, nfo, pkw, bp, ln2_g, ln2_b,
                                         pm1, mlp_b1, pm2, nfo);
    // conv reads xbf(nfo) + costbf; writes bf16 h1 (pixel-major) over xu region
    k_conv_mfma<<<dim3(8, 16, 4), 256, 0, stream>>>(nfo, costbf, pk, bias2, h1bf);
    k_head<<<256, 256, 0, stream>>>(h1bf, w2a, dp_b2, out);
}

// Round 25
// 213.695 us; speedup vs baseline: 1.5407x; 1.5407x over previous
//
#include <hip/hip_runtime.h>
#include <math.h>

// Dims
constexpr int Bn = 4, Cc = 128, Hh = 128, Wn = 128, Dd = 48;
constexpr float SCALE = 0.25f;       // 16^-0.5

typedef short  bf16x8 __attribute__((ext_vector_type(8)));
typedef short  bf16x4 __attribute__((ext_vector_type(4)));
typedef float  f32x4  __attribute__((ext_vector_type(4)));
typedef unsigned short u16x8 __attribute__((ext_vector_type(8)));

static __device__ __forceinline__ unsigned short f2bf(float f) {
    return __builtin_bit_cast(unsigned short, (__bf16)f);
}
static __device__ __forceinline__ float bf2f(unsigned short u) {
    return __uint_as_float((unsigned int)u << 16);
}
static __device__ __forceinline__ unsigned int pack2bf(float a, float b) {
    return (unsigned int)f2bf(a) | ((unsigned int)f2bf(b) << 16);
}
static __device__ __forceinline__ float gelu_f(float v) {
    float u = v * (1.5957691216f + 0.0713548162f * v * v);
    return v * __builtin_amdgcn_rcpf(1.0f + __expf(-u));
}

// Packed-o address: fragment (Mt,ks), lane l, window (b,wh,ww).
static __device__ __forceinline__ size_t opk_addr(int b, int wh, int ww, int Mt, int ks, int lane) {
    return ((size_t)(b * 16384) + (wh * 8 + Mt * 2 + (ks >> 1)) * 128 + ww * 8) * 128
           + (ks & 1) * 512 + lane * 8;
}

// ---------------------------------------------------------------------------
// K1: cost volume -> bf16 pixel-major [b][h][w][64] (d 48..63 zero-padded).
// (staged LDS version — round-23 known-good)
__global__ __launch_bounds__(384) void k_cost(const float* __restrict__ fl,
                                              const float* __restrict__ fr,
                                              unsigned short* __restrict__ costbf) {
    __shared__ float s_fl[2][16][64];
    __shared__ float s_fr[2][16][112];
    int tid = threadIdx.x;
    int w0 = blockIdx.x * 64;
    int hp = blockIdx.y, b = blockIdx.z;
    int row = tid / 192;
    int r = tid - row * 192;
    int wg = r & 15, dg = r >> 4;
    int W = wg * 4, D = dg * 4;
    int h = hp * 2 + row;
    float acc[4][4];
#pragma unroll
    for (int i = 0; i < 4; ++i)
#pragma unroll
        for (int j = 0; j < 4; ++j) acc[i][j] = 0.f;

#pragma unroll 1
    for (int ck = 0; ck < 8; ++ck) {
        int ci0 = ck * 16;
        for (int i = tid; i < 512; i += 384) {
            int rr = i >> 8, rem = i & 255;
            int c = rem >> 4, k4 = rem & 15;
            float4 v = *(const float4*)&fl[((size_t)(b * 128 + ci0 + c) << 14) + (hp * 2 + rr) * 128 + w0 + k4 * 4];
            *(float4*)&s_fl[rr][c][k4 * 4] = v;
        }
        for (int i = tid; i < 896; i += 384) {
            int rr = i / 448, rem = i - rr * 448;
            int c = rem / 28, k4 = rem - c * 28;
            int wgl = w0 - 48 + k4 * 4;
            float4 v = {0.f, 0.f, 0.f, 0.f};
            if (wgl >= 0)
                v = *(const float4*)&fr[((size_t)(b * 128 + ci0 + c) << 14) + (hp * 2 + rr) * 128 + wgl];
            *(float4*)&s_fr[rr][c][k4 * 4] = v;
        }
        __syncthreads();
#pragma unroll
        for (int c = 0; c < 16; ++c) {
            float4 flv = *(const float4*)&s_fl[row][c][W];
            int base = W - D + 44;
            float4 f0 = *(const float4*)&s_fr[row][c][base];
            float4 f1 = *(const float4*)&s_fr[row][c][base + 4];
            float fw[8] = {f0.x, f0.y, f0.z, f0.w, f1.x, f1.y, f1.z, f1.w};
            float fv[4] = {flv.x, flv.y, flv.z, flv.w};
#pragma unroll
            for (int dj = 0; dj < 4; ++dj)
#pragma unroll
                for (int wv = 0; wv < 4; ++wv)
                    acc[dj][wv] += fv[wv] * fw[wv - dj + 4];
        }
        __syncthreads();
    }
    const float inv = 1.0f / 128.0f;
    unsigned short* cb = costbf + ((size_t)(b << 14) + h * 128 + w0 + W) * 64;
    const u16x8 z8 = {0, 0, 0, 0, 0, 0, 0, 0};
#pragma unroll
    for (int wv = 0; wv < 4; ++wv) {
        bf16x4 o4;
#pragma unroll
        for (int dj = 0; dj < 4; ++dj) o4[dj] = (short)f2bf(acc[dj][wv] * inv);
        *(bf16x4*)&cb[wv * 64 + D] = o4;
        if (D == 44) {
            *(u16x8*)&cb[wv * 64 + 48] = z8;
            *(u16x8*)&cb[wv * 64 + 56] = z8;
        }
    }
}

// ---------------------------------------------------------------------------
// Pack helpers fused into one kernel.
static __device__ void pack_conv(int blk, int lane,
                                 const float* __restrict__ w1, const float* __restrict__ b1,
                                 const float* __restrict__ bng, const float* __restrict__ bnb,
                                 unsigned short* __restrict__ pk, float* __restrict__ bias2) {
    const float rs = 0.9999950000374997f;
    int ct = blk % 6;
    int taplin = blk / 6;
    int tap = taplin % 9, chunk = taplin / 9;
    int co = ct * 16 + (lane & 15);
    int cibase = chunk * 32 + (lane >> 4) * 8;
    u16x8 out;
#pragma unroll
    for (int j = 0; j < 8; ++j) {
        int ci = cibase + j;
        float v = 0.f;
        if (co < 88 && ci < 176) v = w1[(size_t)co * 1584 + ci * 9 + tap] * rs * bng[co];
        out[j] = f2bf(v);
    }
    *(u16x8*)(pk + ((size_t)blk * 64 + lane) * 8) = out;
    if (blk == 0) {
        for (int i = lane; i < 96; i += 64)
            bias2[i] = (i < 88) ? (b1[i] * rs * bng[i] + bnb[i]) : 0.f;
    }
}

static __device__ void pack_gemmB(int blk, int lane,
                                  const float* __restrict__ W,
                                  unsigned short* __restrict__ out, int ncols) {
    int ntiles = ncols >> 4;
    int ks = blk & 3;
    int nt = (blk >> 2) % ntiles;
    int kc = blk / (4 * ntiles);
    int col = nt * 16 + (lane & 15);
    int k0 = kc * 128 + ks * 32 + (lane >> 4) * 8;
    u16x8 o;
#pragma unroll
    for (int j = 0; j < 8; ++j) o[j] = f2bf(W[(size_t)(k0 + j) * ncols + col]);
    *(u16x8*)(out + ((size_t)blk * 64 + lane) * 8) = o;
}

// rpb packed for the TRANSPOSED score layout.
static __device__ void pack_rpb(int blk, int lane,
                                const float* __restrict__ rpb, float* __restrict__ pb) {
    int nt = blk & 3, mt = (blk >> 2) & 3, hh = blk >> 4;
    int tq = nt * 16 + (lane & 15);
    int g = lane >> 4;
    float o[4];
#pragma unroll
    for (int rr = 0; rr < 4; ++rr) {
        int tk = mt * 16 + g * 4 + rr;
        int relidx = (((tq >> 3) - (tk >> 3)) + 7) * 15 + ((tq & 7) - (tk & 7)) + 7;
        o[rr] = rpb[relidx * 8 + hh];
    }
    float4 v = {o[0], o[1], o[2], o[3]};
    *(float4*)(pb + ((size_t)blk * 64 + lane) * 4) = v;
}

__global__ __launch_bounds__(64) void k_pack_all(
        const float* __restrict__ dp_w1, const float* __restrict__ dp_b1,
        const float* __restrict__ bn_g, const float* __restrict__ bn_b,
        unsigned short* __restrict__ pk, float* __restrict__ bias2,
        const float* __restrict__ wq, const float* __restrict__ wk,
        const float* __restrict__ wv, const float* __restrict__ wp,
        unsigned short* __restrict__ pkw,
        const float* __restrict__ rpb, float* __restrict__ pb,
        const float* __restrict__ mlp_w1, unsigned short* __restrict__ pm1,
        const float* __restrict__ mlp_w2, unsigned short* __restrict__ pm2,
        const float* __restrict__ un_w1, unsigned short* __restrict__ pu1,
        const float* __restrict__ un_w2, unsigned short* __restrict__ pu2,
        const float* __restrict__ dp_w2, unsigned short* __restrict__ w2a) {
    int blk = blockIdx.x;
    int lane = threadIdx.x;
    if (blk < 324) {
        pack_conv(blk, lane, dp_w1, dp_b1, bn_g, bn_b, pk, bias2);
    } else if (blk < 452) {
        int bb = blk - 324;
        int mat = bb >> 5;
        const float* W = (mat == 0) ? wq : (mat == 1) ? wk : (mat == 2) ? wv : wp;
        pack_gemmB(bb & 31, lane, W, pkw + (size_t)mat * 16384, 128);
    } else if (blk < 580) {
        pack_rpb(blk - 452, lane, rpb, pb);
    } else if (blk < 708) {
        pack_gemmB(blk - 580, lane, mlp_w1, pm1, 512);
    } else if (blk < 836) {
        pack_gemmB(blk - 708, lane, mlp_w2, pm2, 128);
    } else if (blk < 868) {
        pack_gemmB(blk - 836, lane, un_w1, pu1, 128);
    } else if (blk < 900) {
        pack_gemmB(blk - 868, lane, un_w2, pu2, 128);
    } else {
        // w2a: bf16 row-major [48][96]; w2a[d][k] = dp_w2[d][k] (k<88), else 0.
        for (int i = lane; i < 4608; i += 64) {
            int d = i / 96, k = i - d * 96;
            float v = (k < 88) ? dp_w2[d * 88 + k] : 0.f;
            w2a[i] = f2bf(v);
        }
    }
}

// ---------------------------------------------------------------------------
// K2: unary MLP via MFMA + LN1 producer. 1024 blocks x 64 tokens, 4 waves.
// Writes xu in bf16 (token-major) + nf = LN1(tok) (token-major bf16).
__global__ __launch_bounds__(256) void k_unary_mfma(const float* __restrict__ feat_l,
                                                    const unsigned short* __restrict__ pu1,
                                                    const float* __restrict__ b1,
                                                    const unsigned short* __restrict__ pu2,
                                                    const float* __restrict__ b2,
                                                    const float* __restrict__ g1,
                                                    const float* __restrict__ bt1,
                                                    unsigned short* __restrict__ xu,
                                                    unsigned short* __restrict__ nf) {
    __shared__ __align__(16) unsigned short s_a[64 * 136];
    __shared__ __align__(16) unsigned short s_h[64 * 136];
    int tid = threadIdx.x;
    int wid = tid >> 6, lane = tid & 63;
    int g = lane >> 4, t = lane & 15;
    int n0g = blockIdx.x * 64;
    int b = n0g >> 14;
    int nb = n0g & 16383;

    for (int idx = tid; idx < 4096; idx += 256) {
        int c2 = idx >> 6, nl = idx & 63;
        float v0 = feat_l[((size_t)(b * 128 + 2 * c2) << 14) + nb + nl];
        float v1 = feat_l[((size_t)(b * 128 + 2 * c2 + 1) << 14) + nb + nl];
        *(unsigned int*)&s_a[nl * 136 + 2 * c2] = pack2bf(v0, v1);
    }
    __syncthreads();

    // ---- LN1 -> nf (token-major bf16) ----
    {
        int tok = tid >> 2, q = tid & 3;
        float v[32];
#pragma unroll
        for (int i8 = 0; i8 < 4; ++i8) {
            u16x8 r8 = *(const u16x8*)&s_a[tok * 136 + q * 32 + i8 * 8];
#pragma unroll
            for (int j = 0; j < 8; ++j) v[i8 * 8 + j] = bf2f(r8[j]);
        }
        float s = 0.f, s2 = 0.f;
#pragma unroll
        for (int i = 0; i < 32; ++i) { s += v[i]; s2 += v[i] * v[i]; }
        s += __shfl_xor(s, 1); s += __shfl_xor(s, 2);
        s2 += __shfl_xor(s2, 1); s2 += __shfl_xor(s2, 2);
        float mean = s * (1.f / 128.f);
        float var = s2 * (1.f / 128.f) - mean * mean;
        float rstd = rsqrtf(var + 1e-5f);
        size_t base = (size_t)(n0g + tok) * 128 + q * 32;
#pragma unroll
        for (int i8 = 0; i8 < 4; ++i8) {
            u16x8 o8;
#pragma unroll
            for (int j = 0; j < 8; ++j) {
                int c = q * 32 + i8 * 8 + j;
                o8[j] = f2bf((v[i8 * 8 + j] - mean) * rstd * g1[c] + bt1[c]);
            }
            *(u16x8*)&nf[base + i8 * 8] = o8;
        }
    }

    bf16x8 af[4][4];
#pragma unroll
    for (int Mt = 0; Mt < 4; ++Mt)
#pragma unroll
        for (int ks = 0; ks < 4; ++ks)
            af[Mt][ks] = *(const bf16x8*)&s_a[(Mt * 16 + t) * 136 + ks * 32 + g * 8];

    f32x4 acc1[4][2];
#pragma unroll
    for (int nt2 = 0; nt2 < 2; ++nt2) {
        float bv = b1[(wid * 2 + nt2) * 16 + t];
#pragma unroll
        for (int Mt = 0; Mt < 4; ++Mt) acc1[Mt][nt2] = (f32x4){bv, bv, bv, bv};
    }
#pragma unroll
    for (int ks = 0; ks < 4; ++ks) {
        bf16x8 bf0 = *(const bf16x8*)(pu1 + (size_t)(((wid * 2 + 0) * 4 + ks) * 64 + lane) * 8);
        bf16x8 bf1 = *(const bf16x8*)(pu1 + (size_t)(((wid * 2 + 1) * 4 + ks) * 64 + lane) * 8);
#pragma unroll
        for (int Mt = 0; Mt < 4; ++Mt) {
            acc1[Mt][0] = __builtin_amdgcn_mfma_f32_16x16x32_bf16(af[Mt][ks], bf0, acc1[Mt][0], 0, 0, 0);
            acc1[Mt][1] = __builtin_amdgcn_mfma_f32_16x16x32_bf16(af[Mt][ks], bf1, acc1[Mt][1], 0, 0, 0);
        }
    }
#pragma unroll
    for (int Mt = 0; Mt < 4; ++Mt)
#pragma unroll
        for (int nt2 = 0; nt2 < 2; ++nt2)
#pragma unroll
            for (int rr = 0; rr < 4; ++rr)
                s_h[(Mt * 16 + g * 4 + rr) * 136 + (wid * 2 + nt2) * 16 + t] = f2bf(gelu_f(acc1[Mt][nt2][rr]));
    __syncthreads();

    bf16x8 a2[4][4];
#pragma unroll
    for (int Mt = 0; Mt < 4; ++Mt)
#pragma unroll
        for (int ks = 0; ks < 4; ++ks)
            a2[Mt][ks] = *(const bf16x8*)&s_h[(Mt * 16 + t) * 136 + ks * 32 + g * 8];

    f32x4 acc2[4][2];
#pragma unroll
    for (int nt2 = 0; nt2 < 2; ++nt2) {
        float bv = b2[(wid * 2 + nt2) * 16 + t];
#pragma unroll
        for (int Mt = 0; Mt < 4; ++Mt) acc2[Mt][nt2] = (f32x4){bv, bv, bv, bv};
    }
#pragma unroll
    for (int ks = 0; ks < 4; ++ks) {
        bf16x8 bf0 = *(const bf16x8*)(pu2 + (size_t)(((wid * 2 + 0) * 4 + ks) * 64 + lane) * 8);
        bf16x8 bf1 = *(const bf16x8*)(pu2 + (size_t)(((wid * 2 + 1) * 4 + ks) * 64 + lane) * 8);
#pragma unroll
        for (int Mt = 0; Mt < 4; ++Mt) {
            acc2[Mt][0] = __builtin_amdgcn_mfma_f32_16x16x32_bf16(a2[Mt][ks], bf0, acc2[Mt][0], 0, 0, 0);
            acc2[Mt][1] = __builtin_amdgcn_mfma_f32_16x16x32_bf16(a2[Mt][ks], bf1, acc2[Mt][1], 0, 0, 0);
        }
    }
#pragma unroll
    for (int Mt = 0; Mt < 4; ++Mt)
#pragma unroll
        for (int nt2 = 0; nt2 < 2; ++nt2)
#pragma unroll
            for (int rr = 0; rr < 4; ++rr) {
                int tok = Mt * 16 + g * 4 + rr;
                xu[(size_t)(n0g + tok) * 128 + (wid * 2 + nt2) * 16 + t] = f2bf(acc2[Mt][nt2][rr]);
            }
}

// ---------------------------------------------------------------------------
// K3: attention core (S^T = K Q^T form). ONE-WAVE blocks: 4096 x 64.
// blockIdx = window*4 + wid; each wave owns 2 heads + private 5.76 KB LDS
// -> up to 27 waves/CU co-resident (was 4-block lockstep, occupancy 24%).
// Arithmetic bit-identical to the 4-wave version.
__global__ __launch_bounds__(64) void k_attn_core(const unsigned short* nf,
                                                  const unsigned short* __restrict__ pkw,
                                                  const float* __restrict__ pb,
                                                  const float* __restrict__ bq,
                                                  const float* __restrict__ bk,
                                                  const float* __restrict__ bv,
                                                  unsigned short* opk) {
    __shared__ __align__(16) unsigned short s_all[5760];
    int lane = threadIdx.x;
    int g = lane >> 4, t = lane & 15;
    int bw4 = blockIdx.x;
    int wid = bw4 & 3;
    int bw = bw4 >> 2;
    int b = bw >> 8, wh = (bw >> 4) & 15, ww = bw & 15;

    bf16x8 af[4][4];   // [Mt][ks]
#pragma unroll
    for (int Mt = 0; Mt < 4; ++Mt) {
        int tok = Mt * 16 + t;
        size_t gtok = (size_t)(b * 16384) + (wh * 8 + (tok >> 3)) * 128 + ww * 8 + (tok & 7);
#pragma unroll
        for (int ks = 0; ks < 4; ++ks)
            af[Mt][ks] = *(const bf16x8*)&nf[gtok * 128 + ks * 32 + g * 8];
    }

    unsigned short* sQ = s_all;
    unsigned short* sK = sQ + 1536;
    unsigned short* sV = sQ + 4608;
    unsigned short* sP = sQ;
    unsigned short* sO = sQ;

    const bf16x8 z8v = {0, 0, 0, 0, 0, 0, 0, 0};

#pragma unroll
    for (int hi = 0; hi < 2; ++hi) {
        int h = wid + hi * 4;

        float bqv = bq[h * 16 + t], bkv = bk[h * 16 + t], bvv = bv[h * 16 + t];
        f32x4 qa[4], ka[4], va[4];
#pragma unroll
        for (int Mt = 0; Mt < 4; ++Mt) {
            qa[Mt] = (f32x4){bqv, bqv, bqv, bqv};
            ka[Mt] = (f32x4){bkv, bkv, bkv, bkv};
            va[Mt] = (f32x4){bvv, bvv, bvv, bvv};
        }
#pragma unroll
        for (int ks = 0; ks < 4; ++ks) {
            const unsigned short* wbase = pkw + ((size_t)((h * 4 + ks) * 64 + lane) * 8);
            bf16x8 bfq = *(const bf16x8*)(wbase);
            bf16x8 bfk = *(const bf16x8*)(wbase + 16384);
            bf16x8 bfv = *(const bf16x8*)(wbase + 32768);
#pragma unroll
            for (int Mt = 0; Mt < 4; ++Mt) {
                qa[Mt] = __builtin_amdgcn_mfma_f32_16x16x32_bf16(af[Mt][ks], bfq, qa[Mt], 0, 0, 0);
                ka[Mt] = __builtin_amdgcn_mfma_f32_16x16x32_bf16(af[Mt][ks], bfk, ka[Mt], 0, 0, 0);
                va[Mt] = __builtin_amdgcn_mfma_f32_16x16x32_bf16(af[Mt][ks], bfv, va[Mt], 0, 0, 0);
            }
        }
#pragma unroll
        for (int Mt = 0; Mt < 4; ++Mt) {
            bf16x4 vv;
#pragma unroll
            for (int rr = 0; rr < 4; ++rr) {
                int tok = Mt * 16 + g * 4 + rr;
                sQ[tok * 24 + t] = f2bf(qa[Mt][rr] * SCALE);
                sK[tok * 24 + t] = f2bf(ka[Mt][rr]);
                vv[rr] = (short)f2bf(va[Mt][rr]);
            }
            *(bf16x4*)&sV[t * 72 + Mt * 16 + g * 4] = vv;
        }

        // ---- S^T = K Q^T + bias(C-init); pad lanes (g>=2) feed zeros ----
        f32x4 s[4][4];   // [Mtk][Ntq]
#pragma unroll
        for (int Mtk = 0; Mtk < 4; ++Mtk)
#pragma unroll
            for (int Ntq = 0; Ntq < 4; ++Ntq)
                s[Mtk][Ntq] = *(const f32x4*)(pb + ((size_t)((h * 16 + Mtk * 4 + Ntq) * 64 + lane) * 4));
        bf16x8 bQ[4];
#pragma unroll
        for (int Ntq = 0; Ntq < 4; ++Ntq)
            bQ[Ntq] = (g < 2) ? *(const bf16x8*)&sQ[(Ntq * 16 + t) * 24 + g * 8] : z8v;
#pragma unroll
        for (int Mtk = 0; Mtk < 4; ++Mtk) {
            bf16x8 aK = (g < 2) ? *(const bf16x8*)&sK[(Mtk * 16 + t) * 24 + g * 8] : z8v;
#pragma unroll
            for (int Ntq = 0; Ntq < 4; ++Ntq)
                s[Mtk][Ntq] = __builtin_amdgcn_mfma_f32_16x16x32_bf16(aK, bQ[Ntq], s[Mtk][Ntq], 0, 0, 0);
        }

        // ---- softmax: per-lane 16-reduce + 2 shuffles per q-tile ----
#pragma unroll
        for (int Ntq = 0; Ntq < 4; ++Ntq) {
            float m = s[0][Ntq][0];
#pragma unroll
            for (int Mtk = 0; Mtk < 4; ++Mtk)
#pragma unroll
                for (int rr = 0; rr < 4; ++rr) m = fmaxf(m, s[Mtk][Ntq][rr]);
            m = fmaxf(m, __shfl_xor(m, 16));
            m = fmaxf(m, __shfl_xor(m, 32));
            float sum = 0.f;
#pragma unroll
            for (int Mtk = 0; Mtk < 4; ++Mtk)
#pragma unroll
                for (int rr = 0; rr < 4; ++rr) {
                    float e = __expf(s[Mtk][Ntq][rr] - m);
                    s[Mtk][Ntq][rr] = e;
                    sum += e;
                }
            sum += __shfl_xor(sum, 16);
            sum += __shfl_xor(sum, 32);
            float inv = __builtin_amdgcn_rcpf(sum);
#pragma unroll
            for (int Mtk = 0; Mtk < 4; ++Mtk) {
                bf16x4 pv;
#pragma unroll
                for (int rr = 0; rr < 4; ++rr) pv[rr] = (short)f2bf(s[Mtk][Ntq][rr] * inv);
                *(bf16x4*)&sP[(Ntq * 16 + t) * 72 + Mtk * 16 + g * 4] = pv;
            }
        }

        // ---- O = P @ V ----
        f32x4 oa[4];
#pragma unroll
        for (int Mt = 0; Mt < 4; ++Mt) oa[Mt] = (f32x4){0.f, 0.f, 0.f, 0.f};
#pragma unroll
        for (int ksv = 0; ksv < 2; ++ksv) {
            bf16x8 bv2 = *(const bf16x8*)&sV[t * 72 + ksv * 32 + g * 8];
#pragma unroll
            for (int Mt = 0; Mt < 4; ++Mt) {
                bf16x8 ap = *(const bf16x8*)&sP[(Mt * 16 + t) * 72 + ksv * 32 + g * 8];
                oa[Mt] = __builtin_amdgcn_mfma_f32_16x16x32_bf16(ap, bv2, oa[Mt], 0, 0, 0);
            }
        }
#pragma unroll
        for (int Mt = 0; Mt < 4; ++Mt)
#pragma unroll
            for (int rr = 0; rr < 4; ++rr)
                sO[(Mt * 16 + g * 4 + rr) * 16 + t] = f2bf(oa[Mt][rr]);
        int ksf = h >> 1;
        if ((g >> 1) == (h & 1)) {
#pragma unroll
            for (int Mt = 0; Mt < 4; ++Mt) {
                bf16x8 v8 = *(const bf16x8*)&sO[(Mt * 16 + t) * 16 + (g & 1) * 8];
                *(bf16x8*)&opk[opk_addr(b, wh, ww, Mt, ksf, lane)] = v8;
            }
        }
    }
}

// ---------------------------------------------------------------------------
// K4: HALF-WINDOW block: xbf = bf16( (xu + o@wp + bp) + mlp(LN2(...)) ).
// grid 2048: blockIdx = window*2 + half. LDS 18.4 KB -> 8 blocks/CU.
__global__ __launch_bounds__(256) void k_mlp_mfma(const unsigned short* __restrict__ xu,
                                                  const unsigned short* opk,
                                                  const unsigned short* __restrict__ pkw,
                                                  const float* __restrict__ bp,
                                                  const float* __restrict__ g2,
                                                  const float* __restrict__ bt2,
                                                  const unsigned short* __restrict__ pm1,
                                                  const float* __restrict__ b1,
                                                  const unsigned short* __restrict__ pm2,
                                                  unsigned short* xbf) {
    __shared__ __align__(16) char smem[18432];
    float* sf = (float*)smem;                       // [32][132] f32 (16896 B)
    unsigned short* s_h = (unsigned short*)smem;    // [32][264] bf16 overlays sf
    float* s_st = (float*)(smem + 16896);           // [32][2] mean,rstd
    float* s_gb = (float*)(smem + 17152);           // g2[128] | bt2[128]
    int tid = threadIdx.x;
    int wid = tid >> 6, lane = tid & 63;
    int g = lane >> 4, t = lane & 15;
    int bw = blockIdx.x >> 1, half = blockIdx.x & 1;
    int b = bw >> 8, wh = (bw >> 4) & 15, ww = bw & 15;

    auto gtok_of = [&](int tok) -> size_t {   // tok: local 0..31
        int tg = half * 32 + tok;
        return (size_t)(b * 16384) + (wh * 8 + (tg >> 3)) * 128 + ww * 8 + (tg & 7);
    };

    if (tid < 128) s_gb[tid] = g2[tid];
    else if (tid < 256) s_gb[tid] = bt2[tid - 128];

    f32x4 out[2][2];
    {
        float bp0 = bp[wid * 32 + t], bp1 = bp[wid * 32 + 16 + t];
#pragma unroll
        for (int Mt = 0; Mt < 2; ++Mt) {
            out[Mt][0] = (f32x4){bp0, bp0, bp0, bp0};
            out[Mt][1] = (f32x4){bp1, bp1, bp1, bp1};
        }
#pragma unroll
        for (int ks = 0; ks < 4; ++ks) {
            bf16x8 b0 = *(const bf16x8*)(pkw + 49152 + (size_t)(((wid * 2 + 0) * 4 + ks) * 64 + lane) * 8);
            bf16x8 b1v = *(const bf16x8*)(pkw + 49152 + (size_t)(((wid * 2 + 1) * 4 + ks) * 64 + lane) * 8);
#pragma unroll
            for (int Mt = 0; Mt < 2; ++Mt) {
                bf16x8 a = *(const bf16x8*)&opk[opk_addr(b, wh, ww, half * 2 + Mt, ks, lane)];
                out[Mt][0] = __builtin_amdgcn_mfma_f32_16x16x32_bf16(a, b0, out[Mt][0], 0, 0, 0);
                out[Mt][1] = __builtin_amdgcn_mfma_f32_16x16x32_bf16(a, b1v, out[Mt][1], 0, 0, 0);
            }
        }
#pragma unroll
        for (int Mt = 0; Mt < 2; ++Mt)
#pragma unroll
            for (int nt2 = 0; nt2 < 2; ++nt2)
#pragma unroll
                for (int rr = 0; rr < 4; ++rr) {
                    int tok = Mt * 16 + g * 4 + rr;
                    int col = (wid * 2 + nt2) * 16 + t;
                    float v = out[Mt][nt2][rr] + bf2f(xu[gtok_of(tok) * 128 + col]);
                    out[Mt][nt2][rr] = v;
                    sf[tok * 132 + col] = v;
                }
    }
    __syncthreads();
    if (tid < 128) {
        int tok = tid >> 2, q = tid & 3;
        float s = 0.f, s2 = 0.f;
        for (int c = q * 32; c < q * 32 + 32; ++c) {
            float v = sf[tok * 132 + c];
            s += v; s2 += v * v;
        }
        s += __shfl_xor(s, 1); s += __shfl_xor(s, 2);
        s2 += __shfl_xor(s2, 1); s2 += __shfl_xor(s2, 2);
        if (q == 0) {
            float mean = s * (1.f / 128.f);
            float var = s2 * (1.f / 128.f) - mean * mean;
            s_st[tok * 2] = mean;
            s_st[tok * 2 + 1] = rsqrtf(var + 1e-5f);
        }
    }
    __syncthreads();
    bf16x8 af2[2][4];
#pragma unroll
    for (int Mt = 0; Mt < 2; ++Mt) {
        int tok = Mt * 16 + t;
        float mean = s_st[tok * 2], rstd = s_st[tok * 2 + 1];
#pragma unroll
        for (int ks = 0; ks < 4; ++ks) {
            int c0 = ks * 32 + g * 8;
            float4 v0 = *(const float4*)&sf[tok * 132 + c0];
            float4 v1 = *(const float4*)&sf[tok * 132 + c0 + 4];
            float vv[8] = {v0.x, v0.y, v0.z, v0.w, v1.x, v1.y, v1.z, v1.w};
            u16x8 o8;
#pragma unroll
            for (int j = 0; j < 8; ++j)
                o8[j] = f2bf((vv[j] - mean) * rstd * s_gb[c0 + j] + s_gb[128 + c0 + j]);
            af2[Mt][ks] = __builtin_bit_cast(bf16x8, o8);
        }
    }
    __syncthreads();

#pragma unroll 1
    for (int hc = 0; hc < 2; ++hc) {
#pragma unroll
        for (int jh = 0; jh < 2; ++jh) {
            f32x4 acc1[2][2];
#pragma unroll
            for (int j2 = 0; j2 < 2; ++j2) {
                float bv = b1[hc * 256 + (wid * 4 + jh * 2 + j2) * 16 + t];
#pragma unroll
                for (int Mt = 0; Mt < 2; ++Mt) acc1[Mt][j2] = (f32x4){bv, bv, bv, bv};
            }
#pragma unroll
            for (int ks = 0; ks < 4; ++ks) {
                int nt0 = hc * 16 + wid * 4 + jh * 2;
                bf16x8 bf0 = *(const bf16x8*)(pm1 + (size_t)((((nt0 + 0) * 4 + ks) * 64 + lane) * 8));
                bf16x8 bf1 = *(const bf16x8*)(pm1 + (size_t)((((nt0 + 1) * 4 + ks) * 64 + lane) * 8));
#pragma unroll
                for (int Mt = 0; Mt < 2; ++Mt) {
                    acc1[Mt][0] = __builtin_amdgcn_mfma_f32_16x16x32_bf16(af2[Mt][ks], bf0, acc1[Mt][0], 0, 0, 0);
                    acc1[Mt][1] = __builtin_amdgcn_mfma_f32_16x16x32_bf16(af2[Mt][ks], bf1, acc1[Mt][1], 0, 0, 0);
                }
            }
#pragma unroll
            for (int Mt = 0; Mt < 2; ++Mt)
#pragma unroll
                for (int j2 = 0; j2 < 2; ++j2)
#pragma unroll
                    for (int rr = 0; rr < 4; ++rr)
                        s_h[(Mt * 16 + g * 4 + rr) * 264 + (wid * 4 + jh * 2 + j2) * 16 + t] =
                            f2bf(gelu_f(acc1[Mt][j2][rr]));
        }
        __syncthreads();
#pragma unroll
        for (int kt = 0; kt < 8; ++kt) {
            int kc = hc * 2 + (kt >> 2), ks = kt & 3;
            bf16x8 bf0 = *(const bf16x8*)(pm2 + (size_t)(((kc * 32 + (wid * 2 + 0) * 4 + ks) * 64 + lane) * 8));
            bf16x8 bf1 = *(const bf16x8*)(pm2 + (size_t)(((kc * 32 + (wid * 2 + 1) * 4 + ks) * 64 + lane) * 8));
#pragma unroll
            for (int Mt = 0; Mt < 2; ++Mt) {
                bf16x8 a2 = *(const bf16x8*)&s_h[(Mt * 16 + t) * 264 + kt * 32 + g * 8];
                out[Mt][0] = __builtin_amdgcn_mfma_f32_16x16x32_bf16(a2, bf0, out[Mt][0], 0, 0, 0);
                out[Mt][1] = __builtin_amdgcn_mfma_f32_16x16x32_bf16(a2, bf1, out[Mt][1], 0, 0, 0);
            }
        }
        __syncthreads();
    }

    // final: xbf = bf16(x_pre_mlp + mlp_out)
#pragma unroll
    for (int Mt = 0; Mt < 2; ++Mt)
#pragma unroll
        for (int nt2 = 0; nt2 < 2; ++nt2)
#pragma unroll
            for (int rr = 0; rr < 4; ++rr) {
                int tok = Mt * 16 + g * 4 + rr;
                xbf[gtok_of(tok) * 128 + (wid * 2 + nt2) * 16 + t] = f2bf(out[Mt][nt2][rr]);
            }
}

// ---------------------------------------------------------------------------
// K5b: conv3x3 as bf16 implicit-GEMM MFMA. grid (8,16,4) = 512 blocks.
// Writes h1 PIXEL-MAJOR [pix][96]; co 88..95 ZEROED (read by MFMA head pad).
__global__ __launch_bounds__(256) void k_conv_mfma(const unsigned short* __restrict__ xbf,
                                                   const unsigned short* __restrict__ costbf,
                                                   const unsigned short* __restrict__ pk,
                                                   const float* __restrict__ bias2,
                                                   unsigned short* __restrict__ h1) {
    __shared__ __align__(16) unsigned short s_p[180 * 40];
    int tid = threadIdx.x;
    int wid = tid >> 6, lane = tid & 63;
    int g = lane >> 4, t = lane & 15;
    int tx0 = blockIdx.x * 16, ty0 = blockIdx.y * 8, b = blockIdx.z;

    f32x4 acc[2][6];
#pragma unroll
    for (int p = 0; p < 2; ++p)
#pragma unroll
        for (int ct = 0; ct < 6; ++ct) acc[p][ct] = (f32x4){0.f, 0.f, 0.f, 0.f};

#pragma unroll 1
    for (int chunk = 0; chunk < 6; ++chunk) {
        for (int u = tid; u < 180; u += 256) {
            int yy = u / 18, xx = u - yy * 18;
            int gy = ty0 + yy - 1, gx = tx0 + xx - 1;
            u16x8 v0 = (u16x8)(unsigned short)0, v1 = v0, v2 = v0, v3 = v0;
            if (gy >= 0 && gy < 128 && gx >= 0 && gx < 128) {
                size_t pix = (size_t)(b << 14) + gy * 128 + gx;
                const u16x8* src = (chunk < 4)
                    ? (const u16x8*)&xbf[pix * 128 + chunk * 32]
                    : (const u16x8*)&costbf[pix * 64 + (chunk - 4) * 32];
                v0 = src[0]; v1 = src[1]; v2 = src[2]; v3 = src[3];
            }
            *(u16x8*)&s_p[u * 40 + 0] = v0;
            *(u16x8*)&s_p[u * 40 + 8] = v1;
            *(u16x8*)&s_p[u * 40 + 16] = v2;
            *(u16x8*)&s_p[u * 40 + 24] = v3;
        }
        __syncthreads();

#pragma unroll 1
        for (int tap = 0; tap < 9; ++tap) {
            int dy = tap / 3, dx = tap - dy * 3;
            const unsigned short* pkt = pk + ((size_t)(chunk * 9 + tap)) * 6 * 512;
            bf16x8 afr[6];
#pragma unroll
            for (int ct = 0; ct < 6; ++ct)
                afr[ct] = *(const bf16x8*)(pkt + ct * 512 + lane * 8);
            bf16x8 bfr[2];
#pragma unroll
            for (int p = 0; p < 2; ++p) {
                int pos = (wid * 2 + p + dy) * 18 + t + dx;
                bfr[p] = *(const bf16x8*)&s_p[pos * 40 + g * 8];
            }
#pragma unroll
            for (int p = 0; p < 2; ++p)
#pragma unroll
                for (int ct = 0; ct < 6; ++ct)
                    acc[p][ct] = __builtin_amdgcn_mfma_f32_16x16x32_bf16(afr[ct], bfr[p], acc[p][ct], 0, 0, 0);
        }
        __syncthreads();
    }

#pragma unroll
    for (int p = 0; p < 2; ++p) {
        int y = ty0 + wid * 2 + p;
        size_t pix = (size_t)(b << 14) + y * 128 + tx0 + t;
#pragma unroll
        for (int ct = 0; ct < 6; ++ct) {
#pragma unroll
            for (int rr = 0; rr < 4; ++rr) {
                int co = ct * 16 + g * 4 + rr;
                if (co < 88) {
                    float v = acc[p][ct][rr] + bias2[co];
                    h1[pix * 96 + co] = f2bf(fmaxf(v, 0.f));
                } else {
                    h1[pix * 96 + co] = 0;
                }
            }
        }
    }
}

// ---------------------------------------------------------------------------
// K6: head as MFMA GEMM: pv[d=48][px] = w2a[48][96] @ h1^T[96][px] + b2.
__global__ __launch_bounds__(256) void k_head(const unsigned short* __restrict__ h1p,
                                              const unsigned short* __restrict__ w2a,
                                              const float* __restrict__ b2,
                                              float* __restrict__ out) {
    int tid = threadIdx.x;
    int wid = tid >> 6, lane = tid & 63;
    int g = lane >> 4, t = lane & 15;
    int pxb = blockIdx.x * 256 + wid * 64;

    bf16x8 afr[3][3];   // w2a [48][96] row-major: row = Mt*16+t, k = ks*32+g*8
#pragma unroll
    for (int Mt = 0; Mt < 3; ++Mt)
#pragma unroll
        for (int ks = 0; ks < 3; ++ks)
            afr[Mt][ks] = *(const bf16x8*)&w2a[(Mt * 16 + t) * 96 + ks * 32 + g * 8];

    f32x4 acc[3][4];
#pragma unroll
    for (int Mt = 0; Mt < 3; ++Mt) {
        f32x4 bv = *(const f32x4*)&b2[Mt * 16 + g * 4];
#pragma unroll
        for (int nt = 0; nt < 4; ++nt) acc[Mt][nt] = bv;
    }
#pragma unroll
    for (int ks = 0; ks < 3; ++ks) {
#pragma unroll
        for (int nt = 0; nt < 4; ++nt) {
            bf16x8 bfr = *(const bf16x8*)&h1p[(size_t)(pxb + nt * 16 + t) * 96 + ks * 32 + g * 8];
#pragma unroll
            for (int Mt = 0; Mt < 3; ++Mt)
                acc[Mt][nt] = __builtin_amdgcn_mfma_f32_16x16x32_bf16(afr[Mt][ks], bfr, acc[Mt][nt], 0, 0, 0);
        }
    }

#pragma unroll
    for (int nt = 0; nt < 4; ++nt) {
        float m = acc[0][nt][0];
#pragma unroll
        for (int Mt = 0; Mt < 3; ++Mt)
#pragma unroll
            for (int rr = 0; rr < 4; ++rr) m = fmaxf(m, acc[Mt][nt][rr]);
        m = fmaxf(m, __shfl_xor(m, 16));
        m = fmaxf(m, __shfl_xor(m, 32));
        float sum = 0.f, wsum = 0.f;
#pragma unroll
        for (int Mt = 0; Mt < 3; ++Mt)
#pragma unroll
            for (int rr = 0; rr < 4; ++rr) {
                float e = __expf(acc[Mt][nt][rr] - m);
                sum += e;
                wsum += e * (float)(Mt * 16 + g * 4 + rr);
            }
        sum += __shfl_xor(sum, 16);
        sum += __shfl_xor(sum, 32);
        wsum += __shfl_xor(wsum, 16);
        wsum += __shfl_xor(wsum, 32);
        if (g == 0)
            out[pxb + nt * 16 + t] = 4.0f * wsum * __builtin_amdgcn_rcpf(sum);
    }
}

// ---------------------------------------------------------------------------
extern "C" void kernel_launch(void* const* d_in, const int* in_sizes, int n_in,
                              void* d_out, int out_size, void* d_ws, size_t ws_size,
                              hipStream_t stream) {
    const float* feat_l = (const float*)d_in[0];
    const float* feat_r = (const float*)d_in[1];
    const float* wq = (const float*)d_in[2];
    const float* bq = (const float*)d_in[3];
    const float* wk = (const float*)d_in[4];
    const float* bk = (const float*)d_in[5];
    const float* wv = (const float*)d_in[6];
    const float* bv = (const float*)d_in[7];
    const float* wp = (const float*)d_in[8];
    const float* bp = (const float*)d_in[9];
    const float* rpb = (const float*)d_in[10];
    const float* ln1_g = (const float*)d_in[11];
    const float* ln1_b = (const float*)d_in[12];
    const float* ln2_g = (const float*)d_in[13];
    const float* ln2_b = (const float*)d_in[14];
    const float* mlp_w1 = (const float*)d_in[15];
    const float* mlp_b1 = (const float*)d_in[16];
    const float* mlp_w2 = (const float*)d_in[17];
    // d_in[18] = mlp_b2 is multiplied by 0.0 in the reference -> unused
    const float* un_w1 = (const float*)d_in[19];
    const float* un_b1 = (const float*)d_in[20];
    const float* un_w2 = (const float*)d_in[21];
    const float* un_b2 = (const float*)d_in[22];
    const float* dp_w1 = (const float*)d_in[23];
    const float* dp_b1 = (const float*)d_in[24];
    const float* bn_g = (const float*)d_in[25];
    const float* bn_b = (const float*)d_in[26];
    const float* dp_w2 = (const float*)d_in[27];
    const float* dp_b2 = (const float*)d_in[28];

    float* ws = (float*)d_ws;
    unsigned short* costbf = (unsigned short*)ws;   // 4*16384*64 u16 = 8.4 MB
    // xu (unary out, bf16, 16.8 MB) in the old x region; h1bf (pixel-major
    // [pix][96], 12.6 MB) overwrites it after k_mlp has consumed xu.
    unsigned short* xu = (unsigned short*)(ws + 3145728);
    unsigned short* h1bf = (unsigned short*)(ws + 3145728);
    // nf -> opk -> xbf all share this 16.8 MB region (per-window in-place).
    unsigned short* nfo = (unsigned short*)(ws + 11534336);
    unsigned short* pk = (unsigned short*)(ws + 17301504);       // 165,888 u16
    float* bias2 = ws + 17384448;                   // 96 f
    unsigned short* pkw = (unsigned short*)(ws + 17384544);      // 65,536 u16
    float* pb = ws + 17417312;                      // 32,768 f
    unsigned short* pm1 = (unsigned short*)(ws + 17450080);      // 65,536 u16
    unsigned short* pm2 = (unsigned short*)(ws + 17482848);      // 65,536 u16
    unsigned short* pu1 = (unsigned short*)(ws + 17515616);      // 16,384 u16
    unsigned short* pu2 = (unsigned short*)(ws + 17523808);      // 16,384 u16
    unsigned short* w2a = (unsigned short*)(ws + 17532000);      // 4,608 u16 (bf16 head A)
    float* out = (float*)d_out;

    k_pack_all<<<901, 64, 0, stream>>>(dp_w1, dp_b1, bn_g, bn_b, pk, bias2,
                                       wq, wk, wv, wp, pkw, rpb, pb,
                                       mlp_w1, pm1, mlp_w2, pm2,
                                       un_w1, pu1, un_w2, pu2,
                                       dp_w2, w2a);
    k_cost<<<dim3(2, 64, 4), 384, 0, stream>>>(feat_l, feat_r, costbf);
    k_unary_mfma<<<1024, 256, 0, stream>>>(feat_l, pu1, un_b1, pu2, un_b2,
                                           ln1_g, ln1_b, xu, nfo);
    // k_attn: 1-wave blocks (window*4 + wid)
    k_attn_core<<<4096, 64, 0, stream>>>(nfo, pkw, pb, bq, bk, bv, nfo);
    // k_mlp (half-window blocks) reads xu(bf16) + opk(nfo), writes xbf IN PLACE
    k_mlp_mfma<<<2048, 256, 0, stream>>>(xu, nfo, pkw, bp, ln2_g, ln2_b,
                                         pm1, mlp_b1, pm2, nfo);
    // conv reads xbf(nfo) + costbf; writes bf16 h1 (pixel-major) over xu region
    k_conv_mfma<<<dim3(8, 16, 4), 256, 0, stream>>>(nfo, costbf, pk, bias2, h1bf);
    k_head<<<256, 256, 0, stream>>>(h1bf, w2a, dp_b2, out);
}

// Round 26
// 212.753 us; speedup vs baseline: 1.5476x; 1.0044x over previous
//
#include <hip/hip_runtime.h>
#include <math.h>

// Dims
constexpr int Bn = 4, Cc = 128, Hh = 128, Wn = 128, Dd = 48;
constexpr float SCALE = 0.25f;       // 16^-0.5

typedef short  bf16x8 __attribute__((ext_vector_type(8)));
typedef short  bf16x4 __attribute__((ext_vector_type(4)));
typedef float  f32x4  __attribute__((ext_vector_type(4)));
typedef unsigned short u16x8 __attribute__((ext_vector_type(8)));

static __device__ __forceinline__ unsigned short f2bf(float f) {
    return __builtin_bit_cast(unsigned short, (__bf16)f);
}
static __device__ __forceinline__ float bf2f(unsigned short u) {
    return __uint_as_float((unsigned int)u << 16);
}
static __device__ __forceinline__ unsigned int pack2bf(float a, float b) {
    return (unsigned int)f2bf(a) | ((unsigned int)f2bf(b) << 16);
}
static __device__ __forceinline__ float gelu_f(float v) {
    float u = v * (1.5957691216f + 0.0713548162f * v * v);
    return v * __builtin_amdgcn_rcpf(1.0f + __expf(-u));
}

// Packed-o address: fragment (Mt,ks), lane l, window (b,wh,ww).
static __device__ __forceinline__ size_t opk_addr(int b, int wh, int ww, int Mt, int ks, int lane) {
    return ((size_t)(b * 16384) + (wh * 8 + Mt * 2 + (ks >> 1)) * 128 + ww * 8) * 128
           + (ks & 1) * 512 + lane * 8;
}

// ---------------------------------------------------------------------------
// K1: cost volume -> bf16 pixel-major [b][h][w][64] (d 48..63 zero-padded).
__global__ __launch_bounds__(384) void k_cost(const float* __restrict__ fl,
                                              const float* __restrict__ fr,
                                              unsigned short* __restrict__ costbf) {
    __shared__ float s_fl[2][16][64];
    __shared__ float s_fr[2][16][112];
    int tid = threadIdx.x;
    int w0 = blockIdx.x * 64;
    int hp = blockIdx.y, b = blockIdx.z;
    int row = tid / 192;
    int r = tid - row * 192;
    int wg = r & 15, dg = r >> 4;
    int W = wg * 4, D = dg * 4;
    int h = hp * 2 + row;
    float acc[4][4];
#pragma unroll
    for (int i = 0; i < 4; ++i)
#pragma unroll
        for (int j = 0; j < 4; ++j) acc[i][j] = 0.f;

#pragma unroll 1
    for (int ck = 0; ck < 8; ++ck) {
        int ci0 = ck * 16;
        for (int i = tid; i < 512; i += 384) {
            int rr = i >> 8, rem = i & 255;
            int c = rem >> 4, k4 = rem & 15;
            float4 v = *(const float4*)&fl[((size_t)(b * 128 + ci0 + c) << 14) + (hp * 2 + rr) * 128 + w0 + k4 * 4];
            *(float4*)&s_fl[rr][c][k4 * 4] = v;
        }
        for (int i = tid; i < 896; i += 384) {
            int rr = i / 448, rem = i - rr * 448;
            int c = rem / 28, k4 = rem - c * 28;
            int wgl = w0 - 48 + k4 * 4;
            float4 v = {0.f, 0.f, 0.f, 0.f};
            if (wgl >= 0)
                v = *(const float4*)&fr[((size_t)(b * 128 + ci0 + c) << 14) + (hp * 2 + rr) * 128 + wgl];
            *(float4*)&s_fr[rr][c][k4 * 4] = v;
        }
        __syncthreads();
#pragma unroll
        for (int c = 0; c < 16; ++c) {
            float4 flv = *(const float4*)&s_fl[row][c][W];
            int base = W - D + 44;
            float4 f0 = *(const float4*)&s_fr[row][c][base];
            float4 f1 = *(const float4*)&s_fr[row][c][base + 4];
            float fw[8] = {f0.x, f0.y, f0.z, f0.w, f1.x, f1.y, f1.z, f1.w};
            float fv[4] = {flv.x, flv.y, flv.z, flv.w};
#pragma unroll
            for (int dj = 0; dj < 4; ++dj)
#pragma unroll
                for (int wv = 0; wv < 4; ++wv)
                    acc[dj][wv] += fv[wv] * fw[wv - dj + 4];
        }
        __syncthreads();
    }
    const float inv = 1.0f / 128.0f;
    unsigned short* cb = costbf + ((size_t)(b << 14) + h * 128 + w0 + W) * 64;
    const u16x8 z8 = {0, 0, 0, 0, 0, 0, 0, 0};
#pragma unroll
    for (int wv = 0; wv < 4; ++wv) {
        bf16x4 o4;
#pragma unroll
        for (int dj = 0; dj < 4; ++dj) o4[dj] = (short)f2bf(acc[dj][wv] * inv);
        *(bf16x4*)&cb[wv * 64 + D] = o4;
        if (D == 44) {
            *(u16x8*)&cb[wv * 64 + 48] = z8;
            *(u16x8*)&cb[wv * 64 + 56] = z8;
        }
    }
}

// ---------------------------------------------------------------------------
// Pack helpers fused into one kernel.
static __device__ void pack_conv(int blk, int lane,
                                 const float* __restrict__ w1, const float* __restrict__ b1,
                                 const float* __restrict__ bng, const float* __restrict__ bnb,
                                 unsigned short* __restrict__ pk, float* __restrict__ bias2) {
    const float rs = 0.9999950000374997f;
    int ct = blk % 6;
    int taplin = blk / 6;
    int tap = taplin % 9, chunk = taplin / 9;
    int co = ct * 16 + (lane & 15);
    int cibase = chunk * 32 + (lane >> 4) * 8;
    u16x8 out;
#pragma unroll
    for (int j = 0; j < 8; ++j) {
        int ci = cibase + j;
        float v = 0.f;
        if (co < 88 && ci < 176) v = w1[(size_t)co * 1584 + ci * 9 + tap] * rs * bng[co];
        out[j] = f2bf(v);
    }
    *(u16x8*)(pk + ((size_t)blk * 64 + lane) * 8) = out;
    if (blk == 0) {
        for (int i = lane; i < 96; i += 64)
            bias2[i] = (i < 88) ? (b1[i] * rs * bng[i] + bnb[i]) : 0.f;
    }
}

static __device__ void pack_gemmB(int blk, int lane,
                                  const float* __restrict__ W,
                                  unsigned short* __restrict__ out, int ncols) {
    int ntiles = ncols >> 4;
    int ks = blk & 3;
    int nt = (blk >> 2) % ntiles;
    int kc = blk / (4 * ntiles);
    int col = nt * 16 + (lane & 15);
    int k0 = kc * 128 + ks * 32 + (lane >> 4) * 8;
    u16x8 o;
#pragma unroll
    for (int j = 0; j < 8; ++j) o[j] = f2bf(W[(size_t)(k0 + j) * ncols + col]);
    *(u16x8*)(out + ((size_t)blk * 64 + lane) * 8) = o;
}

// rpb packed for the TRANSPOSED score layout.
static __device__ void pack_rpb(int blk, int lane,
                                const float* __restrict__ rpb, float* __restrict__ pb) {
    int nt = blk & 3, mt = (blk >> 2) & 3, hh = blk >> 4;
    int tq = nt * 16 + (lane & 15);
    int g = lane >> 4;
    float o[4];
#pragma unroll
    for (int rr = 0; rr < 4; ++rr) {
        int tk = mt * 16 + g * 4 + rr;
        int relidx = (((tq >> 3) - (tk >> 3)) + 7) * 15 + ((tq & 7) - (tk & 7)) + 7;
        o[rr] = rpb[relidx * 8 + hh];
    }
    float4 v = {o[0], o[1], o[2], o[3]};
    *(float4*)(pb + ((size_t)blk * 64 + lane) * 4) = v;
}

__global__ __launch_bounds__(64) void k_pack_all(
        const float* __restrict__ dp_w1, const float* __restrict__ dp_b1,
        const float* __restrict__ bn_g, const float* __restrict__ bn_b,
        unsigned short* __restrict__ pk, float* __restrict__ bias2,
        const float* __restrict__ wq, const float* __restrict__ wk,
        const float* __restrict__ wv, const float* __restrict__ wp,
        unsigned short* __restrict__ pkw,
        const float* __restrict__ rpb, float* __restrict__ pb,
        const float* __restrict__ mlp_w1, unsigned short* __restrict__ pm1,
        const float* __restrict__ mlp_w2, unsigned short* __restrict__ pm2,
        const float* __restrict__ un_w1, unsigned short* __restrict__ pu1,
        const float* __restrict__ un_w2, unsigned short* __restrict__ pu2,
        const float* __restrict__ dp_w2, unsigned short* __restrict__ w2a) {
    int blk = blockIdx.x;
    int lane = threadIdx.x;
    if (blk < 324) {
        pack_conv(blk, lane, dp_w1, dp_b1, bn_g, bn_b, pk, bias2);
    } else if (blk < 452) {
        int bb = blk - 324;
        int mat = bb >> 5;
        const float* W = (mat == 0) ? wq : (mat == 1) ? wk : (mat == 2) ? wv : wp;
        pack_gemmB(bb & 31, lane, W, pkw + (size_t)mat * 16384, 128);
    } else if (blk < 580) {
        pack_rpb(blk - 452, lane, rpb, pb);
    } else if (blk < 708) {
        pack_gemmB(blk - 580, lane, mlp_w1, pm1, 512);
    } else if (blk < 836) {
        pack_gemmB(blk - 708, lane, mlp_w2, pm2, 128);
    } else if (blk < 868) {
        pack_gemmB(blk - 836, lane, un_w1, pu1, 128);
    } else if (blk < 900) {
        pack_gemmB(blk - 868, lane, un_w2, pu2, 128);
    } else {
        // w2a: bf16 row-major [48][96]; w2a[d][k] = dp_w2[d][k] (k<88), else 0.
        for (int i = lane; i < 4608; i += 64) {
            int d = i / 96, k = i - d * 96;
            float v = (k < 88) ? dp_w2[d * 88 + k] : 0.f;
            w2a[i] = f2bf(v);
        }
    }
}

// ---------------------------------------------------------------------------
// K2: unary MLP via MFMA + LN1 producer. 1024 blocks x 64 tokens, 4 waves.
// Writes xu in bf16 (token-major) + nf = LN1(tok) (token-major bf16).
__global__ __launch_bounds__(256) void k_unary_mfma(const float* __restrict__ feat_l,
                                                    const unsigned short* __restrict__ pu1,
                                                    const float* __restrict__ b1,
                                                    const unsigned short* __restrict__ pu2,
                                                    const float* __restrict__ b2,
                                                    const float* __restrict__ g1,
                                                    const float* __restrict__ bt1,
                                                    unsigned short* __restrict__ xu,
                                                    unsigned short* __restrict__ nf) {
    __shared__ __align__(16) unsigned short s_a[64 * 136];
    __shared__ __align__(16) unsigned short s_h[64 * 136];
    int tid = threadIdx.x;
    int wid = tid >> 6, lane = tid & 63;
    int g = lane >> 4, t = lane & 15;
    int n0g = blockIdx.x * 64;
    int b = n0g >> 14;
    int nb = n0g & 16383;

    for (int idx = tid; idx < 4096; idx += 256) {
        int c2 = idx >> 6, nl = idx & 63;
        float v0 = feat_l[((size_t)(b * 128 + 2 * c2) << 14) + nb + nl];
        float v1 = feat_l[((size_t)(b * 128 + 2 * c2 + 1) << 14) + nb + nl];
        *(unsigned int*)&s_a[nl * 136 + 2 * c2] = pack2bf(v0, v1);
    }
    __syncthreads();

    // ---- LN1 -> nf (token-major bf16) ----
    {
        int tok = tid >> 2, q = tid & 3;
        float v[32];
#pragma unroll
        for (int i8 = 0; i8 < 4; ++i8) {
            u16x8 r8 = *(const u16x8*)&s_a[tok * 136 + q * 32 + i8 * 8];
#pragma unroll
            for (int j = 0; j < 8; ++j) v[i8 * 8 + j] = bf2f(r8[j]);
        }
        float s = 0.f, s2 = 0.f;
#pragma unroll
        for (int i = 0; i < 32; ++i) { s += v[i]; s2 += v[i] * v[i]; }
        s += __shfl_xor(s, 1); s += __shfl_xor(s, 2);
        s2 += __shfl_xor(s2, 1); s2 += __shfl_xor(s2, 2);
        float mean = s * (1.f / 128.f);
        float var = s2 * (1.f / 128.f) - mean * mean;
        float rstd = rsqrtf(var + 1e-5f);
        size_t base = (size_t)(n0g + tok) * 128 + q * 32;
#pragma unroll
        for (int i8 = 0; i8 < 4; ++i8) {
            u16x8 o8;
#pragma unroll
            for (int j = 0; j < 8; ++j) {
                int c = q * 32 + i8 * 8 + j;
                o8[j] = f2bf((v[i8 * 8 + j] - mean) * rstd * g1[c] + bt1[c]);
            }
            *(u16x8*)&nf[base + i8 * 8] = o8;
        }
    }

    bf16x8 af[4][4];
#pragma unroll
    for (int Mt = 0; Mt < 4; ++Mt)
#pragma unroll
        for (int ks = 0; ks < 4; ++ks)
            af[Mt][ks] = *(const bf16x8*)&s_a[(Mt * 16 + t) * 136 + ks * 32 + g * 8];

    f32x4 acc1[4][2];
#pragma unroll
    for (int nt2 = 0; nt2 < 2; ++nt2) {
        float bv = b1[(wid * 2 + nt2) * 16 + t];
#pragma unroll
        for (int Mt = 0; Mt < 4; ++Mt) acc1[Mt][nt2] = (f32x4){bv, bv, bv, bv};
    }
#pragma unroll
    for (int ks = 0; ks < 4; ++ks) {
        bf16x8 bf0 = *(const bf16x8*)(pu1 + (size_t)(((wid * 2 + 0) * 4 + ks) * 64 + lane) * 8);
        bf16x8 bf1 = *(const bf16x8*)(pu1 + (size_t)(((wid * 2 + 1) * 4 + ks) * 64 + lane) * 8);
#pragma unroll
        for (int Mt = 0; Mt < 4; ++Mt) {
            acc1[Mt][0] = __builtin_amdgcn_mfma_f32_16x16x32_bf16(af[Mt][ks], bf0, acc1[Mt][0], 0, 0, 0);
            acc1[Mt][1] = __builtin_amdgcn_mfma_f32_16x16x32_bf16(af[Mt][ks], bf1, acc1[Mt][1], 0, 0, 0);
        }
    }
#pragma unroll
    for (int Mt = 0; Mt < 4; ++Mt)
#pragma unroll
        for (int nt2 = 0; nt2 < 2; ++nt2)
#pragma unroll
            for (int rr = 0; rr < 4; ++rr)
                s_h[(Mt * 16 + g * 4 + rr) * 136 + (wid * 2 + nt2) * 16 + t] = f2bf(gelu_f(acc1[Mt][nt2][rr]));
    __syncthreads();

    bf16x8 a2[4][4];
#pragma unroll
    for (int Mt = 0; Mt < 4; ++Mt)
#pragma unroll
        for (int ks = 0; ks < 4; ++ks)
            a2[Mt][ks] = *(const bf16x8*)&s_h[(Mt * 16 + t) * 136 + ks * 32 + g * 8];

    f32x4 acc2[4][2];
#pragma unroll
    for (int nt2 = 0; nt2 < 2; ++nt2) {
        float bv = b2[(wid * 2 + nt2) * 16 + t];
#pragma unroll
        for (int Mt = 0; Mt < 4; ++Mt) acc2[Mt][nt2] = (f32x4){bv, bv, bv, bv};
    }
#pragma unroll
    for (int ks = 0; ks < 4; ++ks) {
        bf16x8 bf0 = *(const bf16x8*)(pu2 + (size_t)(((wid * 2 + 0) * 4 + ks) * 64 + lane) * 8);
        bf16x8 bf1 = *(const bf16x8*)(pu2 + (size_t)(((wid * 2 + 1) * 4 + ks) * 64 + lane) * 8);
#pragma unroll
        for (int Mt = 0; Mt < 4; ++Mt) {
            acc2[Mt][0] = __builtin_amdgcn_mfma_f32_16x16x32_bf16(a2[Mt][ks], bf0, acc2[Mt][0], 0, 0, 0);
            acc2[Mt][1] = __builtin_amdgcn_mfma_f32_16x16x32_bf16(a2[Mt][ks], bf1, acc2[Mt][1], 0, 0, 0);
        }
    }
#pragma unroll
    for (int Mt = 0; Mt < 4; ++Mt)
#pragma unroll
        for (int nt2 = 0; nt2 < 2; ++nt2)
#pragma unroll
            for (int rr = 0; rr < 4; ++rr) {
                int tok = Mt * 16 + g * 4 + rr;
                xu[(size_t)(n0g + tok) * 128 + (wid * 2 + nt2) * 16 + t] = f2bf(acc2[Mt][nt2][rr]);
            }
}

// ---------------------------------------------------------------------------
// K3: attention core (S^T = K Q^T form). 1024 blocks, 256 threads (4 waves).
__global__ __launch_bounds__(256, 3) void k_attn_core(const unsigned short* nf,
                                                      const unsigned short* __restrict__ pkw,
                                                      const float* __restrict__ pb,
                                                      const float* __restrict__ bq,
                                                      const float* __restrict__ bk,
                                                      const float* __restrict__ bv,
                                                      unsigned short* opk) {
    __shared__ __align__(16) unsigned short s_all[4 * 5760];
    int tid = threadIdx.x;
    int wid = tid >> 6, lane = tid & 63;
    int g = lane >> 4, t = lane & 15;
    int bw = blockIdx.x;
    int b = bw >> 8, wh = (bw >> 4) & 15, ww = bw & 15;

    bf16x8 af[4][4];   // [Mt][ks]
#pragma unroll
    for (int Mt = 0; Mt < 4; ++Mt) {
        int tok = Mt * 16 + t;
        size_t gtok = (size_t)(b * 16384) + (wh * 8 + (tok >> 3)) * 128 + ww * 8 + (tok & 7);
#pragma unroll
        for (int ks = 0; ks < 4; ++ks)
            af[Mt][ks] = *(const bf16x8*)&nf[gtok * 128 + ks * 32 + g * 8];
    }
    __syncthreads();

    unsigned short* sQ = s_all + wid * 5760;
    unsigned short* sK = sQ + 1536;
    unsigned short* sV = sQ + 4608;
    unsigned short* sP = sQ;
    unsigned short* sO = sQ;

    const bf16x8 z8v = {0, 0, 0, 0, 0, 0, 0, 0};

#pragma unroll
    for (int hi = 0; hi < 2; ++hi) {
        int h = wid + hi * 4;

        float bqv = bq[h * 16 + t], bkv = bk[h * 16 + t], bvv = bv[h * 16 + t];
        f32x4 qa[4], ka[4], va[4];
#pragma unroll
        for (int Mt = 0; Mt < 4; ++Mt) {
            qa[Mt] = (f32x4){bqv, bqv, bqv, bqv};
            ka[Mt] = (f32x4){bkv, bkv, bkv, bkv};
            va[Mt] = (f32x4){bvv, bvv, bvv, bvv};
        }
#pragma unroll
        for (int ks = 0; ks < 4; ++ks) {
            const unsigned short* wbase = pkw + ((size_t)((h * 4 + ks) * 64 + lane) * 8);
            bf16x8 bfq = *(const bf16x8*)(wbase);
            bf16x8 bfk = *(const bf16x8*)(wbase + 16384);
            bf16x8 bfv = *(const bf16x8*)(wbase + 32768);
#pragma unroll
            for (int Mt = 0; Mt < 4; ++Mt) {
                qa[Mt] = __builtin_amdgcn_mfma_f32_16x16x32_bf16(af[Mt][ks], bfq, qa[Mt], 0, 0, 0);
                ka[Mt] = __builtin_amdgcn_mfma_f32_16x16x32_bf16(af[Mt][ks], bfk, ka[Mt], 0, 0, 0);
                va[Mt] = __builtin_amdgcn_mfma_f32_16x16x32_bf16(af[Mt][ks], bfv, va[Mt], 0, 0, 0);
            }
        }
#pragma unroll
        for (int Mt = 0; Mt < 4; ++Mt) {
            bf16x4 vv;
#pragma unroll
            for (int rr = 0; rr < 4; ++rr) {
                int tok = Mt * 16 + g * 4 + rr;
                sQ[tok * 24 + t] = f2bf(qa[Mt][rr] * SCALE);
                sK[tok * 24 + t] = f2bf(ka[Mt][rr]);
                vv[rr] = (short)f2bf(va[Mt][rr]);
            }
            *(bf16x4*)&sV[t * 72 + Mt * 16 + g * 4] = vv;
        }

        // ---- S^T = K Q^T + bias(C-init); pad lanes (g>=2) feed zeros ----
        f32x4 s[4][4];   // [Mtk][Ntq]
#pragma unroll
        for (int Mtk = 0; Mtk < 4; ++Mtk)
#pragma unroll
            for (int Ntq = 0; Ntq < 4; ++Ntq)
                s[Mtk][Ntq] = *(const f32x4*)(pb + ((size_t)((h * 16 + Mtk * 4 + Ntq) * 64 + lane) * 4));
        bf16x8 bQ[4];
#pragma unroll
        for (int Ntq = 0; Ntq < 4; ++Ntq)
            bQ[Ntq] = (g < 2) ? *(const bf16x8*)&sQ[(Ntq * 16 + t) * 24 + g * 8] : z8v;
#pragma unroll
        for (int Mtk = 0; Mtk < 4; ++Mtk) {
            bf16x8 aK = (g < 2) ? *(const bf16x8*)&sK[(Mtk * 16 + t) * 24 + g * 8] : z8v;
#pragma unroll
            for (int Ntq = 0; Ntq < 4; ++Ntq)
                s[Mtk][Ntq] = __builtin_amdgcn_mfma_f32_16x16x32_bf16(aK, bQ[Ntq], s[Mtk][Ntq], 0, 0, 0);
        }

        // ---- softmax: per-lane 16-reduce + 2 shuffles per q-tile ----
#pragma unroll
        for (int Ntq = 0; Ntq < 4; ++Ntq) {
            float m = s[0][Ntq][0];
#pragma unroll
            for (int Mtk = 0; Mtk < 4; ++Mtk)
#pragma unroll
                for (int rr = 0; rr < 4; ++rr) m = fmaxf(m, s[Mtk][Ntq][rr]);
            m = fmaxf(m, __shfl_xor(m, 16));
            m = fmaxf(m, __shfl_xor(m, 32));
            float sum = 0.f;
#pragma unroll
            for (int Mtk = 0; Mtk < 4; ++Mtk)
#pragma unroll
                for (int rr = 0; rr < 4; ++rr) {
                    float e = __expf(s[Mtk][Ntq][rr] - m);
                    s[Mtk][Ntq][rr] = e;
                    sum += e;
                }
            sum += __shfl_xor(sum, 16);
            sum += __shfl_xor(sum, 32);
            float inv = __builtin_amdgcn_rcpf(sum);
#pragma unroll
            for (int Mtk = 0; Mtk < 4; ++Mtk) {
                bf16x4 pv;
#pragma unroll
                for (int rr = 0; rr < 4; ++rr) pv[rr] = (short)f2bf(s[Mtk][Ntq][rr] * inv);
                *(bf16x4*)&sP[(Ntq * 16 + t) * 72 + Mtk * 16 + g * 4] = pv;
            }
        }

        // ---- O = P @ V ----
        f32x4 oa[4];
#pragma unroll
        for (int Mt = 0; Mt < 4; ++Mt) oa[Mt] = (f32x4){0.f, 0.f, 0.f, 0.f};
#pragma unroll
        for (int ksv = 0; ksv < 2; ++ksv) {
            bf16x8 bv2 = *(const bf16x8*)&sV[t * 72 + ksv * 32 + g * 8];
#pragma unroll
            for (int Mt = 0; Mt < 4; ++Mt) {
                bf16x8 ap = *(const bf16x8*)&sP[(Mt * 16 + t) * 72 + ksv * 32 + g * 8];
                oa[Mt] = __builtin_amdgcn_mfma_f32_16x16x32_bf16(ap, bv2, oa[Mt], 0, 0, 0);
            }
        }
#pragma unroll
        for (int Mt = 0; Mt < 4; ++Mt)
#pragma unroll
            for (int rr = 0; rr < 4; ++rr)
                sO[(Mt * 16 + g * 4 + rr) * 16 + t] = f2bf(oa[Mt][rr]);
        int ksf = h >> 1;
        if ((g >> 1) == (h & 1)) {
#pragma unroll
            for (int Mt = 0; Mt < 4; ++Mt) {
                bf16x8 v8 = *(const bf16x8*)&sO[(Mt * 16 + t) * 16 + (g & 1) * 8];
                *(bf16x8*)&opk[opk_addr(b, wh, ww, Mt, ksf, lane)] = v8;
            }
        }
    }
}

// ---------------------------------------------------------------------------
// K4: HALF-WINDOW block: xbf = bf16( (xu + o@wp + bp) + mlp(LN2(...)) ).
// grid 2048: blockIdx = window*2 + half. LDS 18.4 KB -> 8 blocks/CU.
__global__ __launch_bounds__(256) void k_mlp_mfma(const unsigned short* __restrict__ xu,
                                                  const unsigned short* opk,
                                                  const unsigned short* __restrict__ pkw,
                                                  const float* __restrict__ bp,
                                                  const float* __restrict__ g2,
                                                  const float* __restrict__ bt2,
                                                  const unsigned short* __restrict__ pm1,
                                                  const float* __restrict__ b1,
                                                  const unsigned short* __restrict__ pm2,
                                                  unsigned short* xbf) {
    __shared__ __align__(16) char smem[18432];
    float* sf = (float*)smem;                       // [32][132] f32 (16896 B)
    unsigned short* s_h = (unsigned short*)smem;    // [32][264] bf16 overlays sf
    float* s_st = (float*)(smem + 16896);           // [32][2] mean,rstd
    float* s_gb = (float*)(smem + 17152);           // g2[128] | bt2[128]
    int tid = threadIdx.x;
    int wid = tid >> 6, lane = tid & 63;
    int g = lane >> 4, t = lane & 15;
    int bw = blockIdx.x >> 1, half = blockIdx.x & 1;
    int b = bw >> 8, wh = (bw >> 4) & 15, ww = bw & 15;

    auto gtok_of = [&](int tok) -> size_t {   // tok: local 0..31
        int tg = half * 32 + tok;
        return (size_t)(b * 16384) + (wh * 8 + (tg >> 3)) * 128 + ww * 8 + (tg & 7);
    };

    if (tid < 128) s_gb[tid] = g2[tid];
    else if (tid < 256) s_gb[tid] = bt2[tid - 128];

    f32x4 out[2][2];
    {
        float bp0 = bp[wid * 32 + t], bp1 = bp[wid * 32 + 16 + t];
#pragma unroll
        for (int Mt = 0; Mt < 2; ++Mt) {
            out[Mt][0] = (f32x4){bp0, bp0, bp0, bp0};
            out[Mt][1] = (f32x4){bp1, bp1, bp1, bp1};
        }
#pragma unroll
        for (int ks = 0; ks < 4; ++ks) {
            bf16x8 b0 = *(const bf16x8*)(pkw + 49152 + (size_t)(((wid * 2 + 0) * 4 + ks) * 64 + lane) * 8);
            bf16x8 b1v = *(const bf16x8*)(pkw + 49152 + (size_t)(((wid * 2 + 1) * 4 + ks) * 64 + lane) * 8);
#pragma unroll
            for (int Mt = 0; Mt < 2; ++Mt) {
                bf16x8 a = *(const bf16x8*)&opk[opk_addr(b, wh, ww, half * 2 + Mt, ks, lane)];
                out[Mt][0] = __builtin_amdgcn_mfma_f32_16x16x32_bf16(a, b0, out[Mt][0], 0, 0, 0);
                out[Mt][1] = __builtin_amdgcn_mfma_f32_16x16x32_bf16(a, b1v, out[Mt][1], 0, 0, 0);
            }
        }
#pragma unroll
        for (int Mt = 0; Mt < 2; ++Mt)
#pragma unroll
            for (int nt2 = 0; nt2 < 2; ++nt2)
#pragma unroll
                for (int rr = 0; rr < 4; ++rr) {
                    int tok = Mt * 16 + g * 4 + rr;
                    int col = (wid * 2 + nt2) * 16 + t;
                    float v = out[Mt][nt2][rr] + bf2f(xu[gtok_of(tok) * 128 + col]);
                    out[Mt][nt2][rr] = v;
                    sf[tok * 132 + col] = v;
                }
    }
    __syncthreads();
    if (tid < 128) {
        int tok = tid >> 2, q = tid & 3;
        float s = 0.f, s2 = 0.f;
        for (int c = q * 32; c < q * 32 + 32; ++c) {
            float v = sf[tok * 132 + c];
            s += v; s2 += v * v;
        }
        s += __shfl_xor(s, 1); s += __shfl_xor(s, 2);
        s2 += __shfl_xor(s2, 1); s2 += __shfl_xor(s2, 2);
        if (q == 0) {
            float mean = s * (1.f / 128.f);
            float var = s2 * (1.f / 128.f) - mean * mean;
            s_st[tok * 2] = mean;
            s_st[tok * 2 + 1] = rsqrtf(var + 1e-5f);
        }
    }
    __syncthreads();
    bf16x8 af2[2][4];
#pragma unroll
    for (int Mt = 0; Mt < 2; ++Mt) {
        int tok = Mt * 16 + t;
        float mean = s_st[tok * 2], rstd = s_st[tok * 2 + 1];
#pragma unroll
        for (int ks = 0; ks < 4; ++ks) {
            int c0 = ks * 32 + g * 8;
            float4 v0 = *(const float4*)&sf[tok * 132 + c0];
            float4 v1 = *(const float4*)&sf[tok * 132 + c0 + 4];
            float vv[8] = {v0.x, v0.y, v0.z, v0.w, v1.x, v1.y, v1.z, v1.w};
            u16x8 o8;
#pragma unroll
            for (int j = 0; j < 8; ++j)
                o8[j] = f2bf((vv[j] - mean) * rstd * s_gb[c0 + j] + s_gb[128 + c0 + j]);
            af2[Mt][ks] = __builtin_bit_cast(bf16x8, o8);
        }
    }
    __syncthreads();

#pragma unroll 1
    for (int hc = 0; hc < 2; ++hc) {
#pragma unroll
        for (int jh = 0; jh < 2; ++jh) {
            f32x4 acc1[2][2];
#pragma unroll
            for (int j2 = 0; j2 < 2; ++j2) {
                float bv = b1[hc * 256 + (wid * 4 + jh * 2 + j2) * 16 + t];
#pragma unroll
                for (int Mt = 0; Mt < 2; ++Mt) acc1[Mt][j2] = (f32x4){bv, bv, bv, bv};
            }
#pragma unroll
            for (int ks = 0; ks < 4; ++ks) {
                int nt0 = hc * 16 + wid * 4 + jh * 2;
                bf16x8 bf0 = *(const bf16x8*)(pm1 + (size_t)((((nt0 + 0) * 4 + ks) * 64 + lane) * 8));
                bf16x8 bf1 = *(const bf16x8*)(pm1 + (size_t)((((nt0 + 1) * 4 + ks) * 64 + lane) * 8));
#pragma unroll
                for (int Mt = 0; Mt < 2; ++Mt) {
                    acc1[Mt][0] = __builtin_amdgcn_mfma_f32_16x16x32_bf16(af2[Mt][ks], bf0, acc1[Mt][0], 0, 0, 0);
                    acc1[Mt][1] = __builtin_amdgcn_mfma_f32_16x16x32_bf16(af2[Mt][ks], bf1, acc1[Mt][1], 0, 0, 0);
                }
            }
#pragma unroll
            for (int Mt = 0; Mt < 2; ++Mt)
#pragma unroll
                for (int j2 = 0; j2 < 2; ++j2)
#pragma unroll
                    for (int rr = 0; rr < 4; ++rr)
                        s_h[(Mt * 16 + g * 4 + rr) * 264 + (wid * 4 + jh * 2 + j2) * 16 + t] =
                            f2bf(gelu_f(acc1[Mt][j2][rr]));
        }
        __syncthreads();
#pragma unroll
        for (int kt = 0; kt < 8; ++kt) {
            int kc = hc * 2 + (kt >> 2), ks = kt & 3;
            bf16x8 bf0 = *(const bf16x8*)(pm2 + (size_t)(((kc * 32 + (wid * 2 + 0) * 4 + ks) * 64 + lane) * 8));
            bf16x8 bf1 = *(const bf16x8*)(pm2 + (size_t)(((kc * 32 + (wid * 2 + 1) * 4 + ks) * 64 + lane) * 8));
#pragma unroll
            for (int Mt = 0; Mt < 2; ++Mt) {
                bf16x8 a2 = *(const bf16x8*)&s_h[(Mt * 16 + t) * 264 + kt * 32 + g * 8];
                out[Mt][0] = __builtin_amdgcn_mfma_f32_16x16x32_bf16(a2, bf0, out[Mt][0], 0, 0, 0);
                out[Mt][1] = __builtin_amdgcn_mfma_f32_16x16x32_bf16(a2, bf1, out[Mt][1], 0, 0, 0);
            }
        }
        __syncthreads();
    }

    // final: xbf = bf16(x_pre_mlp + mlp_out)
#pragma unroll
    for (int Mt = 0; Mt < 2; ++Mt)
#pragma unroll
        for (int nt2 = 0; nt2 < 2; ++nt2)
#pragma unroll
            for (int rr = 0; rr < 4; ++rr) {
                int tok = Mt * 16 + g * 4 + rr;
                xbf[gtok_of(tok) * 128 + (wid * 2 + nt2) * 16 + t] = f2bf(out[Mt][nt2][rr]);
            }
}

// ---------------------------------------------------------------------------
// K5b: conv3x3 as bf16 implicit-GEMM MFMA. grid (8,16,4) = 512 blocks.
// Writes h1 PIXEL-MAJOR [pix][96]; co 88..95 ZEROED (read by MFMA head pad).
__global__ __launch_bounds__(256) void k_conv_mfma(const unsigned short* __restrict__ xbf,
                                                   const unsigned short* __restrict__ costbf,
                                                   const unsigned short* __restrict__ pk,
                                                   const float* __restrict__ bias2,
                                                   unsigned short* __restrict__ h1) {
    __shared__ __align__(16) unsigned short s_p[180 * 40];
    int tid = threadIdx.x;
    int wid = tid >> 6, lane = tid & 63;
    int g = lane >> 4, t = lane & 15;
    int tx0 = blockIdx.x * 16, ty0 = blockIdx.y * 8, b = blockIdx.z;

    f32x4 acc[2][6];
#pragma unroll
    for (int p = 0; p < 2; ++p)
#pragma unroll
        for (int ct = 0; ct < 6; ++ct) acc[p][ct] = (f32x4){0.f, 0.f, 0.f, 0.f};

#pragma unroll 1
    for (int chunk = 0; chunk < 6; ++chunk) {
        for (int u = tid; u < 180; u += 256) {
            int yy = u / 18, xx = u - yy * 18;
            int gy = ty0 + yy - 1, gx = tx0 + xx - 1;
            u16x8 v0 = (u16x8)(unsigned short)0, v1 = v0, v2 = v0, v3 = v0;
            if (gy >= 0 && gy < 128 && gx >= 0 && gx < 128) {
                size_t pix = (size_t)(b << 14) + gy * 128 + gx;
                const u16x8* src = (chunk < 4)
                    ? (const u16x8*)&xbf[pix * 128 + chunk * 32]
                    : (const u16x8*)&costbf[pix * 64 + (chunk - 4) * 32];
                v0 = src[0]; v1 = src[1]; v2 = src[2]; v3 = src[3];
            }
            *(u16x8*)&s_p[u * 40 + 0] = v0;
            *(u16x8*)&s_p[u * 40 + 8] = v1;
            *(u16x8*)&s_p[u * 40 + 16] = v2;
            *(u16x8*)&s_p[u * 40 + 24] = v3;
        }
        __syncthreads();

#pragma unroll 1
        for (int tap = 0; tap < 9; ++tap) {
            int dy = tap / 3, dx = tap - dy * 3;
            const unsigned short* pkt = pk + ((size_t)(chunk * 9 + tap)) * 6 * 512;
            bf16x8 afr[6];
#pragma unroll
            for (int ct = 0; ct < 6; ++ct)
                afr[ct] = *(const bf16x8*)(pkt + ct * 512 + lane * 8);
            bf16x8 bfr[2];
#pragma unroll
            for (int p = 0; p < 2; ++p) {
                int pos = (wid * 2 + p + dy) * 18 + t + dx;
                bfr[p] = *(const bf16x8*)&s_p[pos * 40 + g * 8];
            }
#pragma unroll
            for (int p = 0; p < 2; ++p)
#pragma unroll
                for (int ct = 0; ct < 6; ++ct)
                    acc[p][ct] = __builtin_amdgcn_mfma_f32_16x16x32_bf16(afr[ct], bfr[p], acc[p][ct], 0, 0, 0);
        }
        __syncthreads();
    }

#pragma unroll
    for (int p = 0; p < 2; ++p) {
        int y = ty0 + wid * 2 + p;
        size_t pix = (size_t)(b << 14) + y * 128 + tx0 + t;
#pragma unroll
        for (int ct = 0; ct < 6; ++ct) {
#pragma unroll
            for (int rr = 0; rr < 4; ++rr) {
                int co = ct * 16 + g * 4 + rr;
                if (co < 88) {
                    float v = acc[p][ct][rr] + bias2[co];
                    h1[pix * 96 + co] = f2bf(fmaxf(v, 0.f));
                } else {
                    h1[pix * 96 + co] = 0;
                }
            }
        }
    }
}

// ---------------------------------------------------------------------------
// K6: head as MFMA GEMM: pv[d=48][px] = w2a[48][96] @ h1^T[96][px] + b2.
__global__ __launch_bounds__(256) void k_head(const unsigned short* __restrict__ h1p,
                                              const unsigned short* __restrict__ w2a,
                                              const float* __restrict__ b2,
                                              float* __restrict__ out) {
    int tid = threadIdx.x;
    int wid = tid >> 6, lane = tid & 63;
    int g = lane >> 4, t = lane & 15;
    int pxb = blockIdx.x * 256 + wid * 64;

    bf16x8 afr[3][3];   // w2a [48][96] row-major: row = Mt*16+t, k = ks*32+g*8
#pragma unroll
    for (int Mt = 0; Mt < 3; ++Mt)
#pragma unroll
        for (int ks = 0; ks < 3; ++ks)
            afr[Mt][ks] = *(const bf16x8*)&w2a[(Mt * 16 + t) * 96 + ks * 32 + g * 8];

    f32x4 acc[3][4];
#pragma unroll
    for (int Mt = 0; Mt < 3; ++Mt) {
        f32x4 bv = *(const f32x4*)&b2[Mt * 16 + g * 4];
#pragma unroll
        for (int nt = 0; nt < 4; ++nt) acc[Mt][nt] = bv;
    }
#pragma unroll
    for (int ks = 0; ks < 3; ++ks) {
#pragma unroll
        for (int nt = 0; nt < 4; ++nt) {
            bf16x8 bfr = *(const bf16x8*)&h1p[(size_t)(pxb + nt * 16 + t) * 96 + ks * 32 + g * 8];
#pragma unroll
            for (int Mt = 0; Mt < 3; ++Mt)
                acc[Mt][nt] = __builtin_amdgcn_mfma_f32_16x16x32_bf16(afr[Mt][ks], bfr, acc[Mt][nt], 0, 0, 0);
        }
    }

#pragma unroll
    for (int nt = 0; nt < 4; ++nt) {
        float m = acc[0][nt][0];
#pragma unroll
        for (int Mt = 0; Mt < 3; ++Mt)
#pragma unroll
            for (int rr = 0; rr < 4; ++rr) m = fmaxf(m, acc[Mt][nt][rr]);
        m = fmaxf(m, __shfl_xor(m, 16));
        m = fmaxf(m, __shfl_xor(m, 32));
        float sum = 0.f, wsum = 0.f;
#pragma unroll
        for (int Mt = 0; Mt < 3; ++Mt)
#pragma unroll
            for (int rr = 0; rr < 4; ++rr) {
                float e = __expf(acc[Mt][nt][rr] - m);
                sum += e;
                wsum += e * (float)(Mt * 16 + g * 4 + rr);
            }
        sum += __shfl_xor(sum, 16);
        sum += __shfl_xor(sum, 32);
        wsum += __shfl_xor(wsum, 16);
        wsum += __shfl_xor(wsum, 32);
        if (g == 0)
            out[pxb + nt * 16 + t] = 4.0f * wsum * __builtin_amdgcn_rcpf(sum);
    }
}

// ---------------------------------------------------------------------------
extern "C" void kernel_launch(void* const* d_in, const int* in_sizes, int n_in,
                              void* d_out, int out_size, void* d_ws, size_t ws_size,
                              hipStream_t stream) {
    const float* feat_l = (const float*)d_in[0];
    const float* feat_r = (const float*)d_in[1];
    const float* wq = (const float*)d_in[2];
    const float* bq = (const float*)d_in[3];
    const float* wk = (const float*)d_in[4];
    const float* bk = (const float*)d_in[5];
    const float* wv = (const float*)d_in[6];
    const float* bv = (const float*)d_in[7];
    const float* wp = (const float*)d_in[8];
    const float* bp = (const float*)d_in[9];
    const float* rpb = (const float*)d_in[10];
    const float* ln1_g = (const float*)d_in[11];
    const float* ln1_b = (const float*)d_in[12];
    const float* ln2_g = (const float*)d_in[13];
    const float* ln2_b = (const float*)d_in[14];
    const float* mlp_w1 = (const float*)d_in[15];
    const float* mlp_b1 = (const float*)d_in[16];
    const float* mlp_w2 = (const float*)d_in[17];
    // d_in[18] = mlp_b2 is multiplied by 0.0 in the reference -> unused
    const float* un_w1 = (const float*)d_in[19];
    const float* un_b1 = (const float*)d_in[20];
    const float* un_w2 = (const float*)d_in[21];
    const float* un_b2 = (const float*)d_in[22];
    const float* dp_w1 = (const float*)d_in[23];
    const float* dp_b1 = (const float*)d_in[24];
    const float* bn_g = (const float*)d_in[25];
    const float* bn_b = (const float*)d_in[26];
    const float* dp_w2 = (const float*)d_in[27];
    const float* dp_b2 = (const float*)d_in[28];

    float* ws = (float*)d_ws;
    unsigned short* costbf = (unsigned short*)ws;   // 4*16384*64 u16 = 8.4 MB
    // xu (unary out, bf16, 16.8 MB) in the old x region; h1bf (pixel-major
    // [pix][96], 12.6 MB) overwrites it after k_mlp has consumed xu.
    unsigned short* xu = (unsigned short*)(ws + 3145728);
    unsigned short* h1bf = (unsigned short*)(ws + 3145728);
    // nf -> opk -> xbf all share this 16.8 MB region (per-window in-place).
    unsigned short* nfo = (unsigned short*)(ws + 11534336);
    unsigned short* pk = (unsigned short*)(ws + 17301504);       // 165,888 u16
    float* bias2 = ws + 17384448;                   // 96 f
    unsigned short* pkw = (unsigned short*)(ws + 17384544);      // 65,536 u16
    float* pb = ws + 17417312;                      // 32,768 f
    unsigned short* pm1 = (unsigned short*)(ws + 17450080);      // 65,536 u16
    unsigned short* pm2 = (unsigned short*)(ws + 17482848);      // 65,536 u16
    unsigned short* pu1 = (unsigned short*)(ws + 17515616);      // 16,384 u16
    unsigned short* pu2 = (unsigned short*)(ws + 17523808);      // 16,384 u16
    unsigned short* w2a = (unsigned short*)(ws + 17532000);      // 4,608 u16 (bf16 head A)
    float* out = (float*)d_out;

    k_pack_all<<<901, 64, 0, stream>>>(dp_w1, dp_b1, bn_g, bn_b, pk, bias2,
                                       wq, wk, wv, wp, pkw, rpb, pb,
                                       mlp_w1, pm1, mlp_w2, pm2,
                                       un_w1, pu1, un_w2, pu2,
                                       dp_w2, w2a);
    k_cost<<<dim3(2, 64, 4), 384, 0, stream>>>(feat_l, feat_r, costbf);
    k_unary_mfma<<<1024, 256, 0, stream>>>(feat_l, pu1, un_b1, pu2, un_b2,
                                           ln1_g, ln1_b, xu, nfo);
    k_attn_core<<<1024, 256, 0, stream>>>(nfo, pkw, pb, bq, bk, bv, nfo);
    // k_mlp (half-window blocks) reads xu(bf16) + opk(nfo), writes xbf IN PLACE
    k_mlp_mfma<<<2048, 256, 0, stream>>>(xu, nfo, pkw, bp, ln2_g, ln2_b,
                                         pm1, mlp_b1, pm2, nfo);
    // conv reads xbf(nfo) + costbf; writes bf16 h1 (pixel-major) over xu region
    k_conv_mfma<<<dim3(8, 16, 4), 256, 0, stream>>>(nfo, costbf, pk, bias2, h1bf);
    k_head<<<256, 256, 0, stream>>>(h1bf, w2a, dp_b2, out);
}

// Round 27
// 209.239 us; speedup vs baseline: 1.5736x; 1.0168x over previous
//
#include <hip/hip_runtime.h>
#include <math.h>

// Dims
constexpr int Bn = 4, Cc = 128, Hh = 128, Wn = 128, Dd = 48;
constexpr float SCALE = 0.25f;       // 16^-0.5

typedef short  bf16x8 __attribute__((ext_vector_type(8)));
typedef short  bf16x4 __attribute__((ext_vector_type(4)));
typedef float  f32x4  __attribute__((ext_vector_type(4)));
typedef unsigned short u16x8 __attribute__((ext_vector_type(8)));

static __device__ __forceinline__ unsigned short f2bf(float f) {
    return __builtin_bit_cast(unsigned short, (__bf16)f);
}
static __device__ __forceinline__ float bf2f(unsigned short u) {
    return __uint_as_float((unsigned int)u << 16);
}
static __device__ __forceinline__ unsigned int pack2bf(float a, float b) {
    return (unsigned int)f2bf(a) | ((unsigned int)f2bf(b) << 16);
}
static __device__ __forceinline__ float gelu_f(float v) {
    float u = v * (1.5957691216f + 0.0713548162f * v * v);
    return v * __builtin_amdgcn_rcpf(1.0f + __expf(-u));
}

// Packed-o address: fragment (Mt,ks), lane l, window (b,wh,ww).
static __device__ __forceinline__ size_t opk_addr(int b, int wh, int ww, int Mt, int ks, int lane) {
    return ((size_t)(b * 16384) + (wh * 8 + Mt * 2 + (ks >> 1)) * 128 + ww * 8) * 128
           + (ks & 1) * 512 + lane * 8;
}

// ---------------------------------------------------------------------------
// K1: cost volume -> bf16 pixel-major [b][h][w][64] (d 48..63 zero-padded).
// ONE-ROW blocks: grid (2,128,4) = 1024 blocks x 192 threads, LDS 11 KB ->
// 4 blocks/CU co-resident so the 16 per-block barriers overlap across blocks.
// Same ascending-c summation order -> bit-identical output.
__global__ __launch_bounds__(192) void k_cost(const float* __restrict__ fl,
                                              const float* __restrict__ fr,
                                              unsigned short* __restrict__ costbf) {
    __shared__ float s_fl[16][64];
    __shared__ float s_fr[16][112];
    int tid = threadIdx.x;
    int w0 = blockIdx.x * 64;
    int h = blockIdx.y, b = blockIdx.z;
    int wg = tid & 15, dg = tid >> 4;   // wg 0..15, dg 0..11
    int W = wg * 4, D = dg * 4;
    float acc[4][4];
#pragma unroll
    for (int i = 0; i < 4; ++i)
#pragma unroll
        for (int j = 0; j < 4; ++j) acc[i][j] = 0.f;

#pragma unroll 1
    for (int ck = 0; ck < 8; ++ck) {
        int ci0 = ck * 16;
        for (int i = tid; i < 256; i += 192) {
            int c = i >> 4, k4 = i & 15;
            float4 v = *(const float4*)&fl[((size_t)(b * 128 + ci0 + c) << 14) + h * 128 + w0 + k4 * 4];
            *(float4*)&s_fl[c][k4 * 4] = v;
        }
        for (int i = tid; i < 448; i += 192) {
            int c = i / 28, k4 = i - c * 28;
            int wgl = w0 - 48 + k4 * 4;
            float4 v = {0.f, 0.f, 0.f, 0.f};
            if (wgl >= 0)
                v = *(const float4*)&fr[((size_t)(b * 128 + ci0 + c) << 14) + h * 128 + wgl];
            *(float4*)&s_fr[c][k4 * 4] = v;
        }
        __syncthreads();
#pragma unroll
        for (int c = 0; c < 16; ++c) {
            float4 flv = *(const float4*)&s_fl[c][W];
            int base = W - D + 44;
            float4 f0 = *(const float4*)&s_fr[c][base];
            float4 f1 = *(const float4*)&s_fr[c][base + 4];
            float fw[8] = {f0.x, f0.y, f0.z, f0.w, f1.x, f1.y, f1.z, f1.w};
            float fv[4] = {flv.x, flv.y, flv.z, flv.w};
#pragma unroll
            for (int dj = 0; dj < 4; ++dj)
#pragma unroll
                for (int wv = 0; wv < 4; ++wv)
                    acc[dj][wv] += fv[wv] * fw[wv - dj + 4];
        }
        __syncthreads();
    }
    const float inv = 1.0f / 128.0f;
    unsigned short* cb = costbf + ((size_t)(b << 14) + h * 128 + w0 + W) * 64;
    const u16x8 z8 = {0, 0, 0, 0, 0, 0, 0, 0};
#pragma unroll
    for (int wv = 0; wv < 4; ++wv) {
        bf16x4 o4;
#pragma unroll
        for (int dj = 0; dj < 4; ++dj) o4[dj] = (short)f2bf(acc[dj][wv] * inv);
        *(bf16x4*)&cb[wv * 64 + D] = o4;
        if (D == 44) {
            *(u16x8*)&cb[wv * 64 + 48] = z8;
            *(u16x8*)&cb[wv * 64 + 56] = z8;
        }
    }
}

// ---------------------------------------------------------------------------
// Pack helpers fused into one kernel.
static __device__ void pack_conv(int blk, int lane,
                                 const float* __restrict__ w1, const float* __restrict__ b1,
                                 const float* __restrict__ bng, const float* __restrict__ bnb,
                                 unsigned short* __restrict__ pk, float* __restrict__ bias2) {
    const float rs = 0.9999950000374997f;
    int ct = blk % 6;
    int taplin = blk / 6;
    int tap = taplin % 9, chunk = taplin / 9;
    int co = ct * 16 + (lane & 15);
    int cibase = chunk * 32 + (lane >> 4) * 8;
    u16x8 out;
#pragma unroll
    for (int j = 0; j < 8; ++j) {
        int ci = cibase + j;
        float v = 0.f;
        if (co < 88 && ci < 176) v = w1[(size_t)co * 1584 + ci * 9 + tap] * rs * bng[co];
        out[j] = f2bf(v);
    }
    *(u16x8*)(pk + ((size_t)blk * 64 + lane) * 8) = out;
    if (blk == 0) {
        for (int i = lane; i < 96; i += 64)
            bias2[i] = (i < 88) ? (b1[i] * rs * bng[i] + bnb[i]) : 0.f;
    }
}

static __device__ void pack_gemmB(int blk, int lane,
                                  const float* __restrict__ W,
                                  unsigned short* __restrict__ out, int ncols) {
    int ntiles = ncols >> 4;
    int ks = blk & 3;
    int nt = (blk >> 2) % ntiles;
    int kc = blk / (4 * ntiles);
    int col = nt * 16 + (lane & 15);
    int k0 = kc * 128 + ks * 32 + (lane >> 4) * 8;
    u16x8 o;
#pragma unroll
    for (int j = 0; j < 8; ++j) o[j] = f2bf(W[(size_t)(k0 + j) * ncols + col]);
    *(u16x8*)(out + ((size_t)blk * 64 + lane) * 8) = o;
}

// rpb packed for the TRANSPOSED score layout.
static __device__ void pack_rpb(int blk, int lane,
                                const float* __restrict__ rpb, float* __restrict__ pb) {
    int nt = blk & 3, mt = (blk >> 2) & 3, hh = blk >> 4;
    int tq = nt * 16 + (lane & 15);
    int g = lane >> 4;
    float o[4];
#pragma unroll
    for (int rr = 0; rr < 4; ++rr) {
        int tk = mt * 16 + g * 4 + rr;
        int relidx = (((tq >> 3) - (tk >> 3)) + 7) * 15 + ((tq & 7) - (tk & 7)) + 7;
        o[rr] = rpb[relidx * 8 + hh];
    }
    float4 v = {o[0], o[1], o[2], o[3]};
    *(float4*)(pb + ((size_t)blk * 64 + lane) * 4) = v;
}

__global__ __launch_bounds__(64) void k_pack_all(
        const float* __restrict__ dp_w1, const float* __restrict__ dp_b1,
        const float* __restrict__ bn_g, const float* __restrict__ bn_b,
        unsigned short* __restrict__ pk, float* __restrict__ bias2,
        const float* __restrict__ wq, const float* __restrict__ wk,
        const float* __restrict__ wv, const float* __restrict__ wp,
        unsigned short* __restrict__ pkw,
        const float* __restrict__ rpb, float* __restrict__ pb,
        const float* __restrict__ mlp_w1, unsigned short* __restrict__ pm1,
        const float* __restrict__ mlp_w2, unsigned short* __restrict__ pm2,
        const float* __restrict__ un_w1, unsigned short* __restrict__ pu1,
        const float* __restrict__ un_w2, unsigned short* __restrict__ pu2,
        const float* __restrict__ dp_w2, unsigned short* __restrict__ w2a) {
    int blk = blockIdx.x;
    int lane = threadIdx.x;
    if (blk < 324) {
        pack_conv(blk, lane, dp_w1, dp_b1, bn_g, bn_b, pk, bias2);
    } else if (blk < 452) {
        int bb = blk - 324;
        int mat = bb >> 5;
        const float* W = (mat == 0) ? wq : (mat == 1) ? wk : (mat == 2) ? wv : wp;
        pack_gemmB(bb & 31, lane, W, pkw + (size_t)mat * 16384, 128);
    } else if (blk < 580) {
        pack_rpb(blk - 452, lane, rpb, pb);
    } else if (blk < 708) {
        pack_gemmB(blk - 580, lane, mlp_w1, pm1, 512);
    } else if (blk < 836) {
        pack_gemmB(blk - 708, lane, mlp_w2, pm2, 128);
    } else if (blk < 868) {
        pack_gemmB(blk - 836, lane, un_w1, pu1, 128);
    } else if (blk < 900) {
        pack_gemmB(blk - 868, lane, un_w2, pu2, 128);
    } else {
        // w2a: bf16 row-major [48][96]; w2a[d][k] = dp_w2[d][k] (k<88), else 0.
        for (int i = lane; i < 4608; i += 64) {
            int d = i / 96, k = i - d * 96;
            float v = (k < 88) ? dp_w2[d * 88 + k] : 0.f;
            w2a[i] = f2bf(v);
        }
    }
}

// ---------------------------------------------------------------------------
// K2: unary MLP via MFMA + LN1 producer. 1024 blocks x 64 tokens, 4 waves.
// Writes xu in bf16 (token-major) + nf = LN1(tok) (token-major bf16).
__global__ __launch_bounds__(256) void k_unary_mfma(const float* __restrict__ feat_l,
                                                    const unsigned short* __restrict__ pu1,
                                                    const float* __restrict__ b1,
                                                    const unsigned short* __restrict__ pu2,
                                                    const float* __restrict__ b2,
                                                    const float* __restrict__ g1,
                                                    const float* __restrict__ bt1,
                                                    unsigned short* __restrict__ xu,
                                                    unsigned short* __restrict__ nf) {
    __shared__ __align__(16) unsigned short s_a[64 * 136];
    __shared__ __align__(16) unsigned short s_h[64 * 136];
    int tid = threadIdx.x;
    int wid = tid >> 6, lane = tid & 63;
    int g = lane >> 4, t = lane & 15;
    int n0g = blockIdx.x * 64;
    int b = n0g >> 14;
    int nb = n0g & 16383;

    for (int idx = tid; idx < 4096; idx += 256) {
        int c2 = idx >> 6, nl = idx & 63;
        float v0 = feat_l[((size_t)(b * 128 + 2 * c2) << 14) + nb + nl];
        float v1 = feat_l[((size_t)(b * 128 + 2 * c2 + 1) << 14) + nb + nl];
        *(unsigned int*)&s_a[nl * 136 + 2 * c2] = pack2bf(v0, v1);
    }
    __syncthreads();

    // ---- LN1 -> nf (token-major bf16) ----
    {
        int tok = tid >> 2, q = tid & 3;
        float v[32];
#pragma unroll
        for (int i8 = 0; i8 < 4; ++i8) {
            u16x8 r8 = *(const u16x8*)&s_a[tok * 136 + q * 32 + i8 * 8];
#pragma unroll
            for (int j = 0; j < 8; ++j) v[i8 * 8 + j] = bf2f(r8[j]);
        }
        float s = 0.f, s2 = 0.f;
#pragma unroll
        for (int i = 0; i < 32; ++i) { s += v[i]; s2 += v[i] * v[i]; }
        s += __shfl_xor(s, 1); s += __shfl_xor(s, 2);
        s2 += __shfl_xor(s2, 1); s2 += __shfl_xor(s2, 2);
        float mean = s * (1.f / 128.f);
        float var = s2 * (1.f / 128.f) - mean * mean;
        float rstd = rsqrtf(var + 1e-5f);
        size_t base = (size_t)(n0g + tok) * 128 + q * 32;
#pragma unroll
        for (int i8 = 0; i8 < 4; ++i8) {
            u16x8 o8;
#pragma unroll
            for (int j = 0; j < 8; ++j) {
                int c = q * 32 + i8 * 8 + j;
                o8[j] = f2bf((v[i8 * 8 + j] - mean) * rstd * g1[c] + bt1[c]);
            }
            *(u16x8*)&nf[base + i8 * 8] = o8;
        }
    }

    bf16x8 af[4][4];
#pragma unroll
    for (int Mt = 0; Mt < 4; ++Mt)
#pragma unroll
        for (int ks = 0; ks < 4; ++ks)
            af[Mt][ks] = *(const bf16x8*)&s_a[(Mt * 16 + t) * 136 + ks * 32 + g * 8];

    f32x4 acc1[4][2];
#pragma unroll
    for (int nt2 = 0; nt2 < 2; ++nt2) {
        float bv = b1[(wid * 2 + nt2) * 16 + t];
#pragma unroll
        for (int Mt = 0; Mt < 4; ++Mt) acc1[Mt][nt2] = (f32x4){bv, bv, bv, bv};
    }
#pragma unroll
    for (int ks = 0; ks < 4; ++ks) {
        bf16x8 bf0 = *(const bf16x8*)(pu1 + (size_t)(((wid * 2 + 0) * 4 + ks) * 64 + lane) * 8);
        bf16x8 bf1 = *(const bf16x8*)(pu1 + (size_t)(((wid * 2 + 1) * 4 + ks) * 64 + lane) * 8);
#pragma unroll
        for (int Mt = 0; Mt < 4; ++Mt) {
            acc1[Mt][0] = __builtin_amdgcn_mfma_f32_16x16x32_bf16(af[Mt][ks], bf0, acc1[Mt][0], 0, 0, 0);
            acc1[Mt][1] = __builtin_amdgcn_mfma_f32_16x16x32_bf16(af[Mt][ks], bf1, acc1[Mt][1], 0, 0, 0);
        }
    }
#pragma unroll
    for (int Mt = 0; Mt < 4; ++Mt)
#pragma unroll
        for (int nt2 = 0; nt2 < 2; ++nt2)
#pragma unroll
            for (int rr = 0; rr < 4; ++rr)
                s_h[(Mt * 16 + g * 4 + rr) * 136 + (wid * 2 + nt2) * 16 + t] = f2bf(gelu_f(acc1[Mt][nt2][rr]));
    __syncthreads();

    bf16x8 a2[4][4];
#pragma unroll
    for (int Mt = 0; Mt < 4; ++Mt)
#pragma unroll
        for (int ks = 0; ks < 4; ++ks)
            a2[Mt][ks] = *(const bf16x8*)&s_h[(Mt * 16 + t) * 136 + ks * 32 + g * 8];

    f32x4 acc2[4][2];
#pragma unroll
    for (int nt2 = 0; nt2 < 2; ++nt2) {
        float bv = b2[(wid * 2 + nt2) * 16 + t];
#pragma unroll
        for (int Mt = 0; Mt < 4; ++Mt) acc2[Mt][nt2] = (f32x4){bv, bv, bv, bv};
    }
#pragma unroll
    for (int ks = 0; ks < 4; ++ks) {
        bf16x8 bf0 = *(const bf16x8*)(pu2 + (size_t)(((wid * 2 + 0) * 4 + ks) * 64 + lane) * 8);
        bf16x8 bf1 = *(const bf16x8*)(pu2 + (size_t)(((wid * 2 + 1) * 4 + ks) * 64 + lane) * 8);
#pragma unroll
        for (int Mt = 0; Mt < 4; ++Mt) {
            acc2[Mt][0] = __builtin_amdgcn_mfma_f32_16x16x32_bf16(a2[Mt][ks], bf0, acc2[Mt][0], 0, 0, 0);
            acc2[Mt][1] = __builtin_amdgcn_mfma_f32_16x16x32_bf16(a2[Mt][ks], bf1, acc2[Mt][1], 0, 0, 0);
        }
    }
#pragma unroll
    for (int Mt = 0; Mt < 4; ++Mt)
#pragma unroll
        for (int nt2 = 0; nt2 < 2; ++nt2)
#pragma unroll
            for (int rr = 0; rr < 4; ++rr) {
                int tok = Mt * 16 + g * 4 + rr;
                xu[(size_t)(n0g + tok) * 128 + (wid * 2 + nt2) * 16 + t] = f2bf(acc2[Mt][nt2][rr]);
            }
}

// ---------------------------------------------------------------------------
// K3: attention core (S^T = K Q^T form). 1024 blocks, 256 threads (4 waves).
__global__ __launch_bounds__(256, 3) void k_attn_core(const unsigned short* nf,
                                                      const unsigned short* __restrict__ pkw,
                                                      const float* __restrict__ pb,
                                                      const float* __restrict__ bq,
                                                      const float* __restrict__ bk,
                                                      const float* __restrict__ bv,
                                                      unsigned short* opk) {
    __shared__ __align__(16) unsigned short s_all[4 * 5760];
    int tid = threadIdx.x;
    int wid = tid >> 6, lane = tid & 63;
    int g = lane >> 4, t = lane & 15;
    int bw = blockIdx.x;
    int b = bw >> 8, wh = (bw >> 4) & 15, ww = bw & 15;

    bf16x8 af[4][4];   // [Mt][ks]
#pragma unroll
    for (int Mt = 0; Mt < 4; ++Mt) {
        int tok = Mt * 16 + t;
        size_t gtok = (size_t)(b * 16384) + (wh * 8 + (tok >> 3)) * 128 + ww * 8 + (tok & 7);
#pragma unroll
        for (int ks = 0; ks < 4; ++ks)
            af[Mt][ks] = *(const bf16x8*)&nf[gtok * 128 + ks * 32 + g * 8];
    }
    __syncthreads();

    unsigned short* sQ = s_all + wid * 5760;
    unsigned short* sK = sQ + 1536;
    unsigned short* sV = sQ + 4608;
    unsigned short* sP = sQ;
    unsigned short* sO = sQ;

    const bf16x8 z8v = {0, 0, 0, 0, 0, 0, 0, 0};

#pragma unroll
    for (int hi = 0; hi < 2; ++hi) {
        int h = wid + hi * 4;

        float bqv = bq[h * 16 + t], bkv = bk[h * 16 + t], bvv = bv[h * 16 + t];
        f32x4 qa[4], ka[4], va[4];
#pragma unroll
        for (int Mt = 0; Mt < 4; ++Mt) {
            qa[Mt] = (f32x4){bqv, bqv, bqv, bqv};
            ka[Mt] = (f32x4){bkv, bkv, bkv, bkv};
            va[Mt] = (f32x4){bvv, bvv, bvv, bvv};
        }
#pragma unroll
        for (int ks = 0; ks < 4; ++ks) {
            const unsigned short* wbase = pkw + ((size_t)((h * 4 + ks) * 64 + lane) * 8);
            bf16x8 bfq = *(const bf16x8*)(wbase);
            bf16x8 bfk = *(const bf16x8*)(wbase + 16384);
            bf16x8 bfv = *(const bf16x8*)(wbase + 32768);
#pragma unroll
            for (int Mt = 0; Mt < 4; ++Mt) {
                qa[Mt] = __builtin_amdgcn_mfma_f32_16x16x32_bf16(af[Mt][ks], bfq, qa[Mt], 0, 0, 0);
                ka[Mt] = __builtin_amdgcn_mfma_f32_16x16x32_bf16(af[Mt][ks], bfk, ka[Mt], 0, 0, 0);
                va[Mt] = __builtin_amdgcn_mfma_f32_16x16x32_bf16(af[Mt][ks], bfv, va[Mt], 0, 0, 0);
            }
        }
#pragma unroll
        for (int Mt = 0; Mt < 4; ++Mt) {
            bf16x4 vv;
#pragma unroll
            for (int rr = 0; rr < 4; ++rr) {
                int tok = Mt * 16 + g * 4 + rr;
                sQ[tok * 24 + t] = f2bf(qa[Mt][rr] * SCALE);
                sK[tok * 24 + t] = f2bf(ka[Mt][rr]);
                vv[rr] = (short)f2bf(va[Mt][rr]);
            }
            *(bf16x4*)&sV[t * 72 + Mt * 16 + g * 4] = vv;
        }

        // ---- S^T = K Q^T + bias(C-init); pad lanes (g>=2) feed zeros ----
        f32x4 s[4][4];   // [Mtk][Ntq]
#pragma unroll
        for (int Mtk = 0; Mtk < 4; ++Mtk)
#pragma unroll
            for (int Ntq = 0; Ntq < 4; ++Ntq)
                s[Mtk][Ntq] = *(const f32x4*)(pb + ((size_t)((h * 16 + Mtk * 4 + Ntq) * 64 + lane) * 4));
        bf16x8 bQ[4];
#pragma unroll
        for (int Ntq = 0; Ntq < 4; ++Ntq)
            bQ[Ntq] = (g < 2) ? *(const bf16x8*)&sQ[(Ntq * 16 + t) * 24 + g * 8] : z8v;
#pragma unroll
        for (int Mtk = 0; Mtk < 4; ++Mtk) {
            bf16x8 aK = (g < 2) ? *(const bf16x8*)&sK[(Mtk * 16 + t) * 24 + g * 8] : z8v;
#pragma unroll
            for (int Ntq = 0; Ntq < 4; ++Ntq)
                s[Mtk][Ntq] = __builtin_amdgcn_mfma_f32_16x16x32_bf16(aK, bQ[Ntq], s[Mtk][Ntq], 0, 0, 0);
        }

        // ---- softmax: per-lane 16-reduce + 2 shuffles per q-tile ----
#pragma unroll
        for (int Ntq = 0; Ntq < 4; ++Ntq) {
            float m = s[0][Ntq][0];
#pragma unroll
            for (int Mtk = 0; Mtk < 4; ++Mtk)
#pragma unroll
                for (int rr = 0; rr < 4; ++rr) m = fmaxf(m, s[Mtk][Ntq][rr]);
            m = fmaxf(m, __shfl_xor(m, 16));
            m = fmaxf(m, __shfl_xor(m, 32));
            float sum = 0.f;
#pragma unroll
            for (int Mtk = 0; Mtk < 4; ++Mtk)
#pragma unroll
                for (int rr = 0; rr < 4; ++rr) {
                    float e = __expf(s[Mtk][Ntq][rr] - m);
                    s[Mtk][Ntq][rr] = e;
                    sum += e;
                }
            sum += __shfl_xor(sum, 16);
            sum += __shfl_xor(sum, 32);
            float inv = __builtin_amdgcn_rcpf(sum);
#pragma unroll
            for (int Mtk = 0; Mtk < 4; ++Mtk) {
                bf16x4 pv;
#pragma unroll
                for (int rr = 0; rr < 4; ++rr) pv[rr] = (short)f2bf(s[Mtk][Ntq][rr] * inv);
                *(bf16x4*)&sP[(Ntq * 16 + t) * 72 + Mtk * 16 + g * 4] = pv;
            }
        }

        // ---- O = P @ V ----
        f32x4 oa[4];
#pragma unroll
        for (int Mt = 0; Mt < 4; ++Mt) oa[Mt] = (f32x4){0.f, 0.f, 0.f, 0.f};
#pragma unroll
        for (int ksv = 0; ksv < 2; ++ksv) {
            bf16x8 bv2 = *(const bf16x8*)&sV[t * 72 + ksv * 32 + g * 8];
#pragma unroll
            for (int Mt = 0; Mt < 4; ++Mt) {
                bf16x8 ap = *(const bf16x8*)&sP[(Mt * 16 + t) * 72 + ksv * 32 + g * 8];
                oa[Mt] = __builtin_amdgcn_mfma_f32_16x16x32_bf16(ap, bv2, oa[Mt], 0, 0, 0);
            }
        }
#pragma unroll
        for (int Mt = 0; Mt < 4; ++Mt)
#pragma unroll
            for (int rr = 0; rr < 4; ++rr)
                sO[(Mt * 16 + g * 4 + rr) * 16 + t] = f2bf(oa[Mt][rr]);
        int ksf = h >> 1;
        if ((g >> 1) == (h & 1)) {
#pragma unroll
            for (int Mt = 0; Mt < 4; ++Mt) {
                bf16x8 v8 = *(const bf16x8*)&sO[(Mt * 16 + t) * 16 + (g & 1) * 8];
                *(bf16x8*)&opk[opk_addr(b, wh, ww, Mt, ksf, lane)] = v8;
            }
        }
    }
}

// ---------------------------------------------------------------------------
// K4: HALF-WINDOW block: xbf = bf16( (xu + o@wp + bp) + mlp(LN2(...)) ).
// grid 2048: blockIdx = window*2 + half. LDS 18.4 KB -> 8 blocks/CU.
__global__ __launch_bounds__(256) void k_mlp_mfma(const unsigned short* __restrict__ xu,
                                                  const unsigned short* opk,
                                                  const unsigned short* __restrict__ pkw,
                                                  const float* __restrict__ bp,
                                                  const float* __restrict__ g2,
                                                  const float* __restrict__ bt2,
                                                  const unsigned short* __restrict__ pm1,
                                                  const float* __restrict__ b1,
                                                  const unsigned short* __restrict__ pm2,
                                                  unsigned short* xbf) {
    __shared__ __align__(16) char smem[18432];
    float* sf = (float*)smem;                       // [32][132] f32 (16896 B)
    unsigned short* s_h = (unsigned short*)smem;    // [32][264] bf16 overlays sf
    float* s_st = (float*)(smem + 16896);           // [32][2] mean,rstd
    float* s_gb = (float*)(smem + 17152);           // g2[128] | bt2[128]
    int tid = threadIdx.x;
    int wid = tid >> 6, lane = tid & 63;
    int g = lane >> 4, t = lane & 15;
    int bw = blockIdx.x >> 1, half = blockIdx.x & 1;
    int b = bw >> 8, wh = (bw >> 4) & 15, ww = bw & 15;

    auto gtok_of = [&](int tok) -> size_t {   // tok: local 0..31
        int tg = half * 32 + tok;
        return (size_t)(b * 16384) + (wh * 8 + (tg >> 3)) * 128 + ww * 8 + (tg & 7);
    };

    if (tid < 128) s_gb[tid] = g2[tid];
    else if (tid < 256) s_gb[tid] = bt2[tid - 128];

    f32x4 out[2][2];
    {
        float bp0 = bp[wid * 32 + t], bp1 = bp[wid * 32 + 16 + t];
#pragma unroll
        for (int Mt = 0; Mt < 2; ++Mt) {
            out[Mt][0] = (f32x4){bp0, bp0, bp0, bp0};
            out[Mt][1] = (f32x4){bp1, bp1, bp1, bp1};
        }
#pragma unroll
        for (int ks = 0; ks < 4; ++ks) {
            bf16x8 b0 = *(const bf16x8*)(pkw + 49152 + (size_t)(((wid * 2 + 0) * 4 + ks) * 64 + lane) * 8);
            bf16x8 b1v = *(const bf16x8*)(pkw + 49152 + (size_t)(((wid * 2 + 1) * 4 + ks) * 64 + lane) * 8);
#pragma unroll
            for (int Mt = 0; Mt < 2; ++Mt) {
                bf16x8 a = *(const bf16x8*)&opk[opk_addr(b, wh, ww, half * 2 + Mt, ks, lane)];
                out[Mt][0] = __builtin_amdgcn_mfma_f32_16x16x32_bf16(a, b0, out[Mt][0], 0, 0, 0);
                out[Mt][1] = __builtin_amdgcn_mfma_f32_16x16x32_bf16(a, b1v, out[Mt][1], 0, 0, 0);
            }
        }
#pragma unroll
        for (int Mt = 0; Mt < 2; ++Mt)
#pragma unroll
            for (int nt2 = 0; nt2 < 2; ++nt2)
#pragma unroll
                for (int rr = 0; rr < 4; ++rr) {
                    int tok = Mt * 16 + g * 4 + rr;
                    int col = (wid * 2 + nt2) * 16 + t;
                    float v = out[Mt][nt2][rr] + bf2f(xu[gtok_of(tok) * 128 + col]);
                    out[Mt][nt2][rr] = v;
                    sf[tok * 132 + col] = v;
                }
    }
    __syncthreads();
    if (tid < 128) {
        int tok = tid >> 2, q = tid & 3;
        float s = 0.f, s2 = 0.f;
        for (int c = q * 32; c < q * 32 + 32; ++c) {
            float v = sf[tok * 132 + c];
            s += v; s2 += v * v;
        }
        s += __shfl_xor(s, 1); s += __shfl_xor(s, 2);
        s2 += __shfl_xor(s2, 1); s2 += __shfl_xor(s2, 2);
        if (q == 0) {
            float mean = s * (1.f / 128.f);
            float var = s2 * (1.f / 128.f) - mean * mean;
            s_st[tok * 2] = mean;
            s_st[tok * 2 + 1] = rsqrtf(var + 1e-5f);
        }
    }
    __syncthreads();
    bf16x8 af2[2][4];
#pragma unroll
    for (int Mt = 0; Mt < 2; ++Mt) {
        int tok = Mt * 16 + t;
        float mean = s_st[tok * 2], rstd = s_st[tok * 2 + 1];
#pragma unroll
        for (int ks = 0; ks < 4; ++ks) {
            int c0 = ks * 32 + g * 8;
            float4 v0 = *(const float4*)&sf[tok * 132 + c0];
            float4 v1 = *(const float4*)&sf[tok * 132 + c0 + 4];
            float vv[8] = {v0.x, v0.y, v0.z, v0.w, v1.x, v1.y, v1.z, v1.w};
            u16x8 o8;
#pragma unroll
            for (int j = 0; j < 8; ++j)
                o8[j] = f2bf((vv[j] - mean) * rstd * s_gb[c0 + j] + s_gb[128 + c0 + j]);
            af2[Mt][ks] = __builtin_bit_cast(bf16x8, o8);
        }
    }
    __syncthreads();

#pragma unroll 1
    for (int hc = 0; hc < 2; ++hc) {
#pragma unroll
        for (int jh = 0; jh < 2; ++jh) {
            f32x4 acc1[2][2];
#pragma unroll
            for (int j2 = 0; j2 < 2; ++j2) {
                float bv = b1[hc * 256 + (wid * 4 + jh * 2 + j2) * 16 + t];
#pragma unroll
                for (int Mt = 0; Mt < 2; ++Mt) acc1[Mt][j2] = (f32x4){bv, bv, bv, bv};
            }
#pragma unroll
            for (int ks = 0; ks < 4; ++ks) {
                int nt0 = hc * 16 + wid * 4 + jh * 2;
                bf16x8 bf0 = *(const bf16x8*)(pm1 + (size_t)((((nt0 + 0) * 4 + ks) * 64 + lane) * 8));
                bf16x8 bf1 = *(const bf16x8*)(pm1 + (size_t)((((nt0 + 1) * 4 + ks) * 64 + lane) * 8));
#pragma unroll
                for (int Mt = 0; Mt < 2; ++Mt) {
                    acc1[Mt][0] = __builtin_amdgcn_mfma_f32_16x16x32_bf16(af2[Mt][ks], bf0, acc1[Mt][0], 0, 0, 0);
                    acc1[Mt][1] = __builtin_amdgcn_mfma_f32_16x16x32_bf16(af2[Mt][ks], bf1, acc1[Mt][1], 0, 0, 0);
                }
            }
#pragma unroll
            for (int Mt = 0; Mt < 2; ++Mt)
#pragma unroll
                for (int j2 = 0; j2 < 2; ++j2)
#pragma unroll
                    for (int rr = 0; rr < 4; ++rr)
                        s_h[(Mt * 16 + g * 4 + rr) * 264 + (wid * 4 + jh * 2 + j2) * 16 + t] =
                            f2bf(gelu_f(acc1[Mt][j2][rr]));
        }
        __syncthreads();
#pragma unroll
        for (int kt = 0; kt < 8; ++kt) {
            int kc = hc * 2 + (kt >> 2), ks = kt & 3;
            bf16x8 bf0 = *(const bf16x8*)(pm2 + (size_t)(((kc * 32 + (wid * 2 + 0) * 4 + ks) * 64 + lane) * 8));
            bf16x8 bf1 = *(const bf16x8*)(pm2 + (size_t)(((kc * 32 + (wid * 2 + 1) * 4 + ks) * 64 + lane) * 8));
#pragma unroll
            for (int Mt = 0; Mt < 2; ++Mt) {
                bf16x8 a2 = *(const bf16x8*)&s_h[(Mt * 16 + t) * 264 + kt * 32 + g * 8];
                out[Mt][0] = __builtin_amdgcn_mfma_f32_16x16x32_bf16(a2, bf0, out[Mt][0], 0, 0, 0);
                out[Mt][1] = __builtin_amdgcn_mfma_f32_16x16x32_bf16(a2, bf1, out[Mt][1], 0, 0, 0);
            }
        }
        __syncthreads();
    }

    // final: xbf = bf16(x_pre_mlp + mlp_out)
#pragma unroll
    for (int Mt = 0; Mt < 2; ++Mt)
#pragma unroll
        for (int nt2 = 0; nt2 < 2; ++nt2)
#pragma unroll
            for (int rr = 0; rr < 4; ++rr) {
                int tok = Mt * 16 + g * 4 + rr;
                xbf[gtok_of(tok) * 128 + (wid * 2 + nt2) * 16 + t] = f2bf(out[Mt][nt2][rr]);
            }
}

// ---------------------------------------------------------------------------
// K5b: conv3x3 as bf16 implicit-GEMM MFMA. grid (8,16,4) = 512 blocks.
// Writes h1 PIXEL-MAJOR [pix][96]; co 88..95 ZEROED (read by MFMA head pad).
__global__ __launch_bounds__(256) void k_conv_mfma(const unsigned short* __restrict__ xbf,
                                                   const unsigned short* __restrict__ costbf,
                                                   const unsigned short* __restrict__ pk,
                                                   const float* __restrict__ bias2,
                                                   unsigned short* __restrict__ h1) {
    __shared__ __align__(16) unsigned short s_p[180 * 40];
    int tid = threadIdx.x;
    int wid = tid >> 6, lane = tid & 63;
    int g = lane >> 4, t = lane & 15;
    int tx0 = blockIdx.x * 16, ty0 = blockIdx.y * 8, b = blockIdx.z;

    f32x4 acc[2][6];
#pragma unroll
    for (int p = 0; p < 2; ++p)
#pragma unroll
        for (int ct = 0; ct < 6; ++ct) acc[p][ct] = (f32x4){0.f, 0.f, 0.f, 0.f};

#pragma unroll 1
    for (int chunk = 0; chunk < 6; ++chunk) {
        for (int u = tid; u < 180; u += 256) {
            int yy = u / 18, xx = u - yy * 18;
            int gy = ty0 + yy - 1, gx = tx0 + xx - 1;
            u16x8 v0 = (u16x8)(unsigned short)0, v1 = v0, v2 = v0, v3 = v0;
            if (gy >= 0 && gy < 128 && gx >= 0 && gx < 128) {
                size_t pix = (size_t)(b << 14) + gy * 128 + gx;
                const u16x8* src = (chunk < 4)
                    ? (const u16x8*)&xbf[pix * 128 + chunk * 32]
                    : (const u16x8*)&costbf[pix * 64 + (chunk - 4) * 32];
                v0 = src[0]; v1 = src[1]; v2 = src[2]; v3 = src[3];
            }
            *(u16x8*)&s_p[u * 40 + 0] = v0;
            *(u16x8*)&s_p[u * 40 + 8] = v1;
            *(u16x8*)&s_p[u * 40 + 16] = v2;
            *(u16x8*)&s_p[u * 40 + 24] = v3;
        }
        __syncthreads();

#pragma unroll 1
        for (int tap = 0; tap < 9; ++tap) {
            int dy = tap / 3, dx = tap - dy * 3;
            const unsigned short* pkt = pk + ((size_t)(chunk * 9 + tap)) * 6 * 512;
            bf16x8 afr[6];
#pragma unroll
            for (int ct = 0; ct < 6; ++ct)
                afr[ct] = *(const bf16x8*)(pkt + ct * 512 + lane * 8);
            bf16x8 bfr[2];
#pragma unroll
            for (int p = 0; p < 2; ++p) {
                int pos = (wid * 2 + p + dy) * 18 + t + dx;
                bfr[p] = *(const bf16x8*)&s_p[pos * 40 + g * 8];
            }
#pragma unroll
            for (int p = 0; p < 2; ++p)
#pragma unroll
                for (int ct = 0; ct < 6; ++ct)
                    acc[p][ct] = __builtin_amdgcn_mfma_f32_16x16x32_bf16(afr[ct], bfr[p], acc[p][ct], 0, 0, 0);
        }
        __syncthreads();
    }

#pragma unroll
    for (int p = 0; p < 2; ++p) {
        int y = ty0 + wid * 2 + p;
        size_t pix = (size_t)(b << 14) + y * 128 + tx0 + t;
#pragma unroll
        for (int ct = 0; ct < 6; ++ct) {
#pragma unroll
            for (int rr = 0; rr < 4; ++rr) {
                int co = ct * 16 + g * 4 + rr;
                if (co < 88) {
                    float v = acc[p][ct][rr] + bias2[co];
                    h1[pix * 96 + co] = f2bf(fmaxf(v, 0.f));
                } else {
                    h1[pix * 96 + co] = 0;
                }
            }
        }
    }
}

// ---------------------------------------------------------------------------
// K6: head as MFMA GEMM: pv[d=48][px] = w2a[48][96] @ h1^T[96][px] + b2.
__global__ __launch_bounds__(256) void k_head(const unsigned short* __restrict__ h1p,
                                              const unsigned short* __restrict__ w2a,
                                              const float* __restrict__ b2,
                                              float* __restrict__ out) {
    int tid = threadIdx.x;
    int wid = tid >> 6, lane = tid & 63;
    int g = lane >> 4, t = lane & 15;
    int pxb = blockIdx.x * 256 + wid * 64;

    bf16x8 afr[3][3];   // w2a [48][96] row-major: row = Mt*16+t, k = ks*32+g*8
#pragma unroll
    for (int Mt = 0; Mt < 3; ++Mt)
#pragma unroll
        for (int ks = 0; ks < 3; ++ks)
            afr[Mt][ks] = *(const bf16x8*)&w2a[(Mt * 16 + t) * 96 + ks * 32 + g * 8];

    f32x4 acc[3][4];
#pragma unroll
    for (int Mt = 0; Mt < 3; ++Mt) {
        f32x4 bv = *(const f32x4*)&b2[Mt * 16 + g * 4];
#pragma unroll
        for (int nt = 0; nt < 4; ++nt) acc[Mt][nt] = bv;
    }
#pragma unroll
    for (int ks = 0; ks < 3; ++ks) {
#pragma unroll
        for (int nt = 0; nt < 4; ++nt) {
            bf16x8 bfr = *(const bf16x8*)&h1p[(size_t)(pxb + nt * 16 + t) * 96 + ks * 32 + g * 8];
#pragma unroll
            for (int Mt = 0; Mt < 3; ++Mt)
                acc[Mt][nt] = __builtin_amdgcn_mfma_f32_16x16x32_bf16(afr[Mt][ks], bfr, acc[Mt][nt], 0, 0, 0);
        }
    }

#pragma unroll
    for (int nt = 0; nt < 4; ++nt) {
        float m = acc[0][nt][0];
#pragma unroll
        for (int Mt = 0; Mt < 3; ++Mt)
#pragma unroll
            for (int rr = 0; rr < 4; ++rr) m = fmaxf(m, acc[Mt][nt][rr]);
        m = fmaxf(m, __shfl_xor(m, 16));
        m = fmaxf(m, __shfl_xor(m, 32));
        float sum = 0.f, wsum = 0.f;
#pragma unroll
        for (int Mt = 0; Mt < 3; ++Mt)
#pragma unroll
            for (int rr = 0; rr < 4; ++rr) {
                float e = __expf(acc[Mt][nt][rr] - m);
                sum += e;
                wsum += e * (float)(Mt * 16 + g * 4 + rr);
            }
        sum += __shfl_xor(sum, 16);
        sum += __shfl_xor(sum, 32);
        wsum += __shfl_xor(wsum, 16);
        wsum += __shfl_xor(wsum, 32);
        if (g == 0)
            out[pxb + nt * 16 + t] = 4.0f * wsum * __builtin_amdgcn_rcpf(sum);
    }
}

// ---------------------------------------------------------------------------
extern "C" void kernel_launch(void* const* d_in, const int* in_sizes, int n_in,
                              void* d_out, int out_size, void* d_ws, size_t ws_size,
                              hipStream_t stream) {
    const float* feat_l = (const float*)d_in[0];
    const float* feat_r = (const float*)d_in[1];
    const float* wq = (const float*)d_in[2];
    const float* bq = (const float*)d_in[3];
    const float* wk = (const float*)d_in[4];
    const float* bk = (const float*)d_in[5];
    const float* wv = (const float*)d_in[6];
    const float* bv = (const float*)d_in[7];
    const float* wp = (const float*)d_in[8];
    const float* bp = (const float*)d_in[9];
    const float* rpb = (const float*)d_in[10];
    const float* ln1_g = (const float*)d_in[11];
    const float* ln1_b = (const float*)d_in[12];
    const float* ln2_g = (const float*)d_in[13];
    const float* ln2_b = (const float*)d_in[14];
    const float* mlp_w1 = (const float*)d_in[15];
    const float* mlp_b1 = (const float*)d_in[16];
    const float* mlp_w2 = (const float*)d_in[17];
    // d_in[18] = mlp_b2 is multiplied by 0.0 in the reference -> unused
    const float* un_w1 = (const float*)d_in[19];
    const float* un_b1 = (const float*)d_in[20];
    const float* un_w2 = (const float*)d_in[21];
    const float* un_b2 = (const float*)d_in[22];
    const float* dp_w1 = (const float*)d_in[23];
    const float* dp_b1 = (const float*)d_in[24];
    const float* bn_g = (const float*)d_in[25];
    const float* bn_b = (const float*)d_in[26];
    const float* dp_w2 = (const float*)d_in[27];
    const float* dp_b2 = (const float*)d_in[28];

    float* ws = (float*)d_ws;
    unsigned short* costbf = (unsigned short*)ws;   // 4*16384*64 u16 = 8.4 MB
    // xu (unary out, bf16, 16.8 MB) in the old x region; h1bf (pixel-major
    // [pix][96], 12.6 MB) overwrites it after k_mlp has consumed xu.
    unsigned short* xu = (unsigned short*)(ws + 3145728);
    unsigned short* h1bf = (unsigned short*)(ws + 3145728);
    // nf -> opk -> xbf all share this 16.8 MB region (per-window in-place).
    unsigned short* nfo = (unsigned short*)(ws + 11534336);
    unsigned short* pk = (unsigned short*)(ws + 17301504);       // 165,888 u16
    float* bias2 = ws + 17384448;                   // 96 f
    unsigned short* pkw = (unsigned short*)(ws + 17384544);      // 65,536 u16
    float* pb = ws + 17417312;                      // 32,768 f
    unsigned short* pm1 = (unsigned short*)(ws + 17450080);      // 65,536 u16
    unsigned short* pm2 = (unsigned short*)(ws + 17482848);      // 65,536 u16
    unsigned short* pu1 = (unsigned short*)(ws + 17515616);      // 16,384 u16
    unsigned short* pu2 = (unsigned short*)(ws + 17523808);      // 16,384 u16
    unsigned short* w2a = (unsigned short*)(ws + 17532000);      // 4,608 u16 (bf16 head A)
    float* out = (float*)d_out;

    k_pack_all<<<901, 64, 0, stream>>>(dp_w1, dp_b1, bn_g, bn_b, pk, bias2,
                                       wq, wk, wv, wp, pkw, rpb, pb,
                                       mlp_w1, pm1, mlp_w2, pm2,
                                       un_w1, pu1, un_w2, pu2,
                                       dp_w2, w2a);
    k_cost<<<dim3(2, 128, 4), 192, 0, stream>>>(feat_l, feat_r, costbf);
    k_unary_mfma<<<1024, 256, 0, stream>>>(feat_l, pu1, un_b1, pu2, un_b2,
                                           ln1_g, ln1_b, xu, nfo);
    k_attn_core<<<1024, 256, 0, stream>>>(nfo, pkw, pb, bq, bk, bv, nfo);
    // k_mlp (half-window blocks) reads xu(bf16) + opk(nfo), writes xbf IN PLACE
    k_mlp_mfma<<<2048, 256, 0, stream>>>(xu, nfo, pkw, bp, ln2_g, ln2_b,
                                         pm1, mlp_b1, pm2, nfo);
    // conv reads xbf(nfo) + costbf; writes bf16 h1 (pixel-major) over xu region
    k_conv_mfma<<<dim3(8, 16, 4), 256, 0, stream>>>(nfo, costbf, pk, bias2, h1bf);
    k_head<<<256, 256, 0, stream>>>(h1bf, w2a, dp_b2, out);
}